// Round 9
// baseline (439.583 us; speedup 1.0000x reference)
//
#include <hip/hip_runtime.h>
#include <cstdint>

#define N_NODES 50000
#define N_EDGES 800000
#define DIM     256
#define BSZ     256
#define ND_     5000
#define KNB     16
#define ER_     20000
#define LAM     0.7f

typedef unsigned int uint;
typedef unsigned short ushort;
typedef __attribute__((ext_vector_type(8))) short bf16x8;
typedef __attribute__((ext_vector_type(4))) float f32x4;

#define MTILES_PAD 3128            // ceil(50000/16) padded to multiple of 4
#define NB_SCAN    ((N_NODES + 255) / 256)   // 196

__device__ __forceinline__ ushort f2bf(float f) {
    uint u = __float_as_uint(f);
    uint r = u + 0x7FFFu + ((u >> 16) & 1u);   // round-to-nearest-even
    return (ushort)(r >> 16);
}
__device__ __forceinline__ float bflo(uint u) { return __uint_as_float(u << 16); }
__device__ __forceinline__ float bfhi(uint u) { return __uint_as_float(u & 0xffff0000u); }

// fragment k-map: elem j, lane-group lg -> kk in [0,32)
// same bijection for A-frag and B-pack (permutation cancels): kk=(j&3)+lg*4+(j>>2)*16
// A-frag elem j<4 : A[row][kt*32 + lg*4 + j]     (16 contiguous B fp32 / 8 B bf16)
// A-frag elem j>=4: A[row][kt*32 + lg*4 + 16 + (j&3)]

__device__ __forceinline__ bf16x8 make_af_f32(const float* __restrict__ A,
                                              int row, int c0, int M) {
    float4 v0 = make_float4(0.f, 0.f, 0.f, 0.f);
    float4 v1 = make_float4(0.f, 0.f, 0.f, 0.f);
    if (row < M) {
        v0 = *(const float4*)(A + (size_t)row * 256 + c0);
        v1 = *(const float4*)(A + (size_t)row * 256 + c0 + 16);
    }
    uint4 o;
    o.x = (uint)f2bf(v0.x) | ((uint)f2bf(v0.y) << 16);
    o.y = (uint)f2bf(v0.z) | ((uint)f2bf(v0.w) << 16);
    o.z = (uint)f2bf(v1.x) | ((uint)f2bf(v1.y) << 16);
    o.w = (uint)f2bf(v1.z) | ((uint)f2bf(v1.w) << 16);
    return *(bf16x8*)&o;
}
__device__ __forceinline__ bf16x8 make_af_bf16(const ushort* __restrict__ A,
                                               int row, int c0, int M) {
    uint2 v0 = make_uint2(0u, 0u), v1 = make_uint2(0u, 0u);
    if (row < M) {
        v0 = *(const uint2*)(A + (size_t)row * 256 + c0);
        v1 = *(const uint2*)(A + (size_t)row * 256 + c0 + 16);
    }
    uint4 o; o.x = v0.x; o.y = v0.y; o.z = v1.x; o.w = v1.y;
    return *(bf16x8*)&o;
}

// ------------------------------------- pack W [K=256,N=256] f32 -> frag order
__global__ __launch_bounds__(256)
void pack_b_kernel(const float* __restrict__ W, ushort* __restrict__ out) {
    const int nt = blockIdx.x;      // 16
    const int t  = threadIdx.x;
    const int l  = t & 63;
    const int kt0 = (t >> 6) * 2;
    const int n  = nt * 16 + (l & 15);
    const int lg = l >> 4;
#pragma unroll
    for (int p = 0; p < 2; ++p) {
        int kt = kt0 + p;
        ushort us[8];
#pragma unroll
        for (int j = 0; j < 8; ++j) {
            int kk = (j & 3) + lg * 4 + (j >> 2) * 16;
            us[j] = f2bf(W[(size_t)(kt * 32 + kk) * 256 + n]);
        }
        ushort* dst = out + ((size_t)(nt * 8 + kt) * 64 + l) * 8;
        *(uint4*)dst = *(uint4*)us;
    }
}

// ------------- bf16 MFMA GEMM, direct row-major A load + fused dots epilogue
// H[M,256] (bf16 row-major) = A @ B ; hs/hd = H @ a_src / H @ a_dst
template<int SRCF32>
__global__ __launch_bounds__(256)
void gemm_bf16_kernel(const float* __restrict__ Af, const ushort* __restrict__ Ab,
                      const ushort* __restrict__ Bp, ushort* __restrict__ H,
                      const float* __restrict__ a_src, const float* __restrict__ a_dst,
                      float* __restrict__ hs, float* __restrict__ hd, int M) {
    __shared__ float sdS[4][64];
    __shared__ float sdD[4][64];
    const int t = threadIdx.x;
    const int w = t >> 6;
    const int l = t & 63;
    const int mt0 = blockIdx.x * 4;
    const int cb  = (l & 15);
    const int lg  = l >> 4;
    f32x4 acc[4][4];
#pragma unroll
    for (int i = 0; i < 4; ++i)
#pragma unroll
        for (int j = 0; j < 4; ++j) acc[i][j] = (f32x4){0.f, 0.f, 0.f, 0.f};

    for (int kt = 0; kt < 8; ++kt) {
        bf16x8 af[4], bfr[4];
        const int c0 = kt * 32 + lg * 4;
#pragma unroll
        for (int mi = 0; mi < 4; ++mi) {
            int row = (mt0 + mi) * 16 + cb;
            af[mi] = SRCF32 ? make_af_f32(Af, row, c0, M)
                            : make_af_bf16(Ab, row, c0, M);
        }
#pragma unroll
        for (int ni = 0; ni < 4; ++ni)
            bfr[ni] = *(const bf16x8*)(Bp + ((size_t)((w * 4 + ni) * 8 + kt) * 64 + l) * 8);
#pragma unroll
        for (int mi = 0; mi < 4; ++mi)
#pragma unroll
            for (int ni = 0; ni < 4; ++ni)
                acc[mi][ni] = __builtin_amdgcn_mfma_f32_16x16x32_bf16(
                    af[mi], bfr[ni], acc[mi][ni], 0, 0, 0);
    }
    const int rbase = (l >> 4) * 4;   // C/D: col=lane&15, row=(lane>>4)*4+reg  [m89/m91]
    float asv[4], adv[4];
#pragma unroll
    for (int ni = 0; ni < 4; ++ni) {
        int col = (w * 4 + ni) * 16 + cb;
        asv[ni] = a_src[col];
        adv[ni] = a_dst[col];
    }
#pragma unroll
    for (int mi = 0; mi < 4; ++mi) {
#pragma unroll
        for (int r = 0; r < 4; ++r) {
            int row = (mt0 + mi) * 16 + rbase + r;
            float ps = 0.f, pd = 0.f;
#pragma unroll
            for (int ni = 0; ni < 4; ++ni) {
                float hv = acc[mi][ni][r];
                ps = fmaf(hv, asv[ni], ps);
                pd = fmaf(hv, adv[ni], pd);
                if (row < M) {
                    int col = (w * 4 + ni) * 16 + cb;
                    H[(size_t)row * 256 + col] = f2bf(hv);
                }
            }
#pragma unroll
            for (int o = 1; o < 16; o <<= 1) {
                ps += __shfl_xor(ps, o);
                pd += __shfl_xor(pd, o);
            }
            if (cb == 0) {
                sdS[w][mi * 16 + rbase + r] = ps;
                sdD[w][mi * 16 + rbase + r] = pd;
            }
        }
    }
    __syncthreads();
    if (t < 64) {
        int row = mt0 * 16 + t;
        if (row < M) {
            hs[row] = sdS[0][t] + sdS[1][t] + sdS[2][t] + sdS[3][t];
            hd[row] = sdD[0][t] + sdD[1][t] + sdD[2][t] + sdD[3][t];
        }
    }
}

// -------------------------------------------------------------- CSR build
__global__ __launch_bounds__(256)
void hist_kernel(const int* __restrict__ ei, int* __restrict__ deg) {
    int e = blockIdx.x * 256 + threadIdx.x;
    if (e < N_EDGES) atomicAdd(&deg[ei[N_EDGES + e]], 1);
}

// -------- two-level parallel exclusive scan of deg -> offs --------
__global__ __launch_bounds__(256)
void blockscan_kernel(const int* __restrict__ deg, int* __restrict__ off,
                      int* __restrict__ bsum) {
    __shared__ int s[256];
    const int b = blockIdx.x, t = threadIdx.x;
    const int idx = b * 256 + t;
    int v = (idx < N_NODES) ? deg[idx] : 0;
    s[t] = v;
    __syncthreads();
    for (int o = 1; o < 256; o <<= 1) {
        int x = (t >= o) ? s[t - o] : 0;
        __syncthreads();
        s[t] += x;
        __syncthreads();
    }
    if (idx < N_NODES) off[idx] = s[t] - v;    // exclusive within block
    if (t == 255) bsum[b] = s[255];
}

__global__ __launch_bounds__(256)
void scan_bsum_kernel(const int* __restrict__ bsum, int* __restrict__ bpre) {
    __shared__ int s[256];
    const int t = threadIdx.x;
    int v = (t < NB_SCAN) ? bsum[t] : 0;
    s[t] = v;
    __syncthreads();
    for (int o = 1; o < 256; o <<= 1) {
        int x = (t >= o) ? s[t - o] : 0;
        __syncthreads();
        s[t] += x;
        __syncthreads();
    }
    if (t < NB_SCAN) bpre[t] = s[t] - v;       // exclusive block prefix
}

__global__ __launch_bounds__(256)
void add_offsets_kernel(int* __restrict__ off, const int* __restrict__ bpre) {
    const int b = blockIdx.x, t = threadIdx.x;
    const int idx = b * 256 + t;
    if (idx < N_NODES) off[idx] += bpre[b];
}

// scatter uses off[] itself as the insertion cursor (atomicAdd returns slot).
// After this kernel, off[d] == original off[d+1]; node d's range is
// [d ? off[d-1] : 0, off[d]).
__global__ __launch_bounds__(256)
void scatter_kernel(const int* __restrict__ ei, int* __restrict__ off,
                    int* __restrict__ csr_src) {
    int e = blockIdx.x * 256 + threadIdx.x;
    if (e >= N_EDGES) return;
    int d = ei[N_EDGES + e];
    int pos = atomicAdd(&off[d], 1);
    csr_src[pos] = ei[e];
}

// ----------------- fused GAT edge stage: wave-per-dst, no max, no barriers
// software-pipelined gather: next 4 rows issued before current 4 consumed.
__global__ __launch_bounds__(256)
void gat_aggr_kernel(const int* __restrict__ off, const int* __restrict__ csr_src,
                     const float* __restrict__ hs, const float* __restrict__ hd,
                     const ushort* __restrict__ hb, const float* __restrict__ bias,
                     float* __restrict__ out_f32, ushort* __restrict__ out_bf,
                     int do_silu) {
    const int d = blockIdx.x * 4 + (threadIdx.x >> 6);
    const int l = threadIdx.x & 63;
    if (d >= N_NODES) return;
    const int beg = d ? off[d - 1] : 0;
    const int end = off[d];
    const float hdd = hd[d];

    float acc0 = 0.f, acc1 = 0.f, acc2 = 0.f, acc3 = 0.f;
    float zl = 0.f;
    const ushort* __restrict__ hcol = hb + l * 4;

    for (int c0 = beg; c0 < end; c0 += 64) {
        const int cn = min(end - c0, 64);
        int s = 0; float pexp = 0.f;
        if (l < cn) {
            s = csr_src[c0 + l];
            float v = hs[s] + hdd;
            v = (v >= 0.f) ? v : 0.2f * v;
            pexp = __expf(v);
        }
        zl += pexp;
        const int nb4 = cn & ~3;
        int j = 0;
        if (nb4) {
            int s0 = __shfl(s, 0), s1 = __shfl(s, 1), s2 = __shfl(s, 2), s3 = __shfl(s, 3);
            uint2 r0 = *(const uint2*)(hcol + (size_t)s0 * DIM);
            uint2 r1 = *(const uint2*)(hcol + (size_t)s1 * DIM);
            uint2 r2 = *(const uint2*)(hcol + (size_t)s2 * DIM);
            uint2 r3 = *(const uint2*)(hcol + (size_t)s3 * DIM);
            for (j = 4; j < nb4; j += 4) {
                int sn0 = __shfl(s, j),     sn1 = __shfl(s, j + 1);
                int sn2 = __shfl(s, j + 2), sn3 = __shfl(s, j + 3);
                uint2 q0 = *(const uint2*)(hcol + (size_t)sn0 * DIM);
                uint2 q1 = *(const uint2*)(hcol + (size_t)sn1 * DIM);
                uint2 q2 = *(const uint2*)(hcol + (size_t)sn2 * DIM);
                uint2 q3 = *(const uint2*)(hcol + (size_t)sn3 * DIM);
                float p0 = __shfl(pexp, j - 4), p1 = __shfl(pexp, j - 3);
                float p2 = __shfl(pexp, j - 2), p3 = __shfl(pexp, j - 1);
                acc0 = fmaf(p0, bflo(r0.x), acc0); acc1 = fmaf(p0, bfhi(r0.x), acc1);
                acc2 = fmaf(p0, bflo(r0.y), acc2); acc3 = fmaf(p0, bfhi(r0.y), acc3);
                acc0 = fmaf(p1, bflo(r1.x), acc0); acc1 = fmaf(p1, bfhi(r1.x), acc1);
                acc2 = fmaf(p1, bflo(r1.y), acc2); acc3 = fmaf(p1, bfhi(r1.y), acc3);
                acc0 = fmaf(p2, bflo(r2.x), acc0); acc1 = fmaf(p2, bfhi(r2.x), acc1);
                acc2 = fmaf(p2, bflo(r2.y), acc2); acc3 = fmaf(p2, bfhi(r2.y), acc3);
                acc0 = fmaf(p3, bflo(r3.x), acc0); acc1 = fmaf(p3, bfhi(r3.x), acc1);
                acc2 = fmaf(p3, bflo(r3.y), acc2); acc3 = fmaf(p3, bfhi(r3.y), acc3);
                r0 = q0; r1 = q1; r2 = q2; r3 = q3;
            }
            float p0 = __shfl(pexp, j - 4), p1 = __shfl(pexp, j - 3);
            float p2 = __shfl(pexp, j - 2), p3 = __shfl(pexp, j - 1);
            acc0 = fmaf(p0, bflo(r0.x), acc0); acc1 = fmaf(p0, bfhi(r0.x), acc1);
            acc2 = fmaf(p0, bflo(r0.y), acc2); acc3 = fmaf(p0, bfhi(r0.y), acc3);
            acc0 = fmaf(p1, bflo(r1.x), acc0); acc1 = fmaf(p1, bfhi(r1.x), acc1);
            acc2 = fmaf(p1, bflo(r1.y), acc2); acc3 = fmaf(p1, bfhi(r1.y), acc3);
            acc0 = fmaf(p2, bflo(r2.x), acc0); acc1 = fmaf(p2, bfhi(r2.x), acc1);
            acc2 = fmaf(p2, bflo(r2.y), acc2); acc3 = fmaf(p2, bfhi(r2.y), acc3);
            acc0 = fmaf(p3, bflo(r3.x), acc0); acc1 = fmaf(p3, bfhi(r3.x), acc1);
            acc2 = fmaf(p3, bflo(r3.y), acc2); acc3 = fmaf(p3, bfhi(r3.y), acc3);
        }
        for (; j < cn; ++j) {
            int   sj = __shfl(s, j);
            float pj = __shfl(pexp, j);
            uint2 rv = *(const uint2*)(hcol + (size_t)sj * DIM);
            acc0 = fmaf(pj, bflo(rv.x), acc0); acc1 = fmaf(pj, bfhi(rv.x), acc1);
            acc2 = fmaf(pj, bflo(rv.y), acc2); acc3 = fmaf(pj, bfhi(rv.y), acc3);
        }
    }
    float z = zl;
#pragma unroll
    for (int o = 32; o; o >>= 1) z += __shfl_xor(z, o);
    const float inv = (end > beg) ? 1.f / (z + 1e-16f) : 0.f;
    float4 bb = *(const float4*)(bias + l * 4);
    float o0 = acc0 * inv + bb.x;
    float o1 = acc1 * inv + bb.y;
    float o2 = acc2 * inv + bb.z;
    float o3 = acc3 * inv + bb.w;
    if (do_silu) {
        o0 = o0 / (1.f + __expf(-o0));
        o1 = o1 / (1.f + __expf(-o1));
        o2 = o2 / (1.f + __expf(-o2));
        o3 = o3 / (1.f + __expf(-o3));
    }
    if (out_bf) {
        ushort us[4] = {f2bf(o0), f2bf(o1), f2bf(o2), f2bf(o3)};
        *(uint2*)(out_bf + (size_t)d * DIM + l * 4) = *(uint2*)us;
    } else {
        *(float4*)(out_f32 + (size_t)d * DIM + l * 4) = make_float4(o0, o1, o2, o3);
    }
}

// ------------------------------- rel-degree histogram (scan prep)
__global__ __launch_bounds__(256)
void rel_hist_kernel(const int* __restrict__ res, int* __restrict__ rhist) {
    int i = blockIdx.x * 256 + threadIdx.x;
    if (i < 3 * ER_) atomicAdd(&rhist[(i / ER_) * ND_ + res[i]], 1);
}

// ----------- conflict detection (flags pre-zeroed by the fused memset).
// Step b writes row head[b] (if disease); reads rows nbs[g2l[head[b]]] ∪ {head[b]}.
// Symmetric flagging: both reader and writer flagged on intersection, so
// unflagged steps touch rows NO other step reads or writes.
__global__ __launch_bounds__(256)
void conflict_kernel(const int* __restrict__ head, const int* __restrict__ rel,
                     const int* __restrict__ g2l, const int* __restrict__ nbs,
                     int* __restrict__ flags) {
    int b = blockIdx.x;
    int rb = rel[b];
    if (rb < 4 || rb > 6) return;
    __shared__ int rd[KNB + 1];
    int t = threadIdx.x;
    if (t == 0) rd[KNB] = head[b];
    if (t < KNB) rd[t] = nbs[(size_t)g2l[head[b]] * KNB + t];
    __syncthreads();
    int rt = rel[t];
    int w = (t != b && rt >= 4 && rt <= 6) ? head[t] : -1;
    if (w >= 0) {
        bool hit = false;
#pragma unroll
        for (int k = 0; k <= KNB; ++k) hit |= (rd[k] == w);
        if (hit) { flags[b] = 1; flags[t] = 1; }
    }
}

// ----------- fused apply: blocks 0..255 = independent (par) steps, reading
// emb directly (their rows are untouched by any other step); block 256 = the
// flagged steps walked in program order (each thread owns one column -> no
// barriers needed in the walk). Par and seq touch disjoint rows -> concurrent.
__global__ __launch_bounds__(256)
void apply_kernel(float* __restrict__ emb, const int* __restrict__ head,
                  const int* __restrict__ rel, const int* __restrict__ g2l,
                  const int* __restrict__ nbs, const float* __restrict__ wts,
                  const int* __restrict__ rhist, const int* __restrict__ flags) {
    const int t = threadIdx.x;
    if (blockIdx.x < BSZ) {
        int b = blockIdx.x;
        int r = rel[b];
        if (r < 4 || r > 6) return;
        if (flags[b]) return;
        int hi = head[b];
        int local = g2l[hi];
        int dg = rhist[(r - 4) * ND_ + local];
        float c = LAM * __expf(-LAM * (float)dg) + 0.2f;
        const int* __restrict__ nb = nbs + (size_t)local * KNB;
        const float* __restrict__ w = wts + (size_t)local * KNB;
        float v0 = 0.f, v1 = 0.f;
#pragma unroll
        for (int k = 0; k < KNB; k += 2) {
            v0 = fmaf(w[k],     emb[(size_t)nb[k] * DIM + t],     v0);
            v1 = fmaf(w[k + 1], emb[(size_t)nb[k + 1] * DIM + t], v1);
        }
        size_t idx = (size_t)hi * DIM + t;
        emb[idx] = c * (v0 + v1) + (1.f - c) * emb[idx];
        return;
    }
    // ---- sequential block ----
    __shared__ int   snb[BSZ][KNB];
    __shared__ float sw[BSZ][KNB];
    __shared__ int   sh[BSZ];
    __shared__ float sc[BSZ];
    __shared__ int   sf[BSZ];
    int r = rel[t];
    int dis = (r >= 4 && r <= 6);
    int hi = head[t];
    sh[t] = hi;
    sf[t] = dis ? flags[t] : 0;
    if (dis) {
        int local = g2l[hi];
        int dg = rhist[(r - 4) * ND_ + local];
        sc[t] = LAM * __expf(-LAM * (float)dg) + 0.2f;
#pragma unroll
        for (int k = 0; k < KNB; ++k) {
            snb[t][k] = nbs[(size_t)local * KNB + k];
            sw[t][k]  = wts[(size_t)local * KNB + k];
        }
    }
    __syncthreads();
    for (int b = 0; b < BSZ; ++b) {
        if (sf[b]) {
            int hh = sh[b];
            float c = sc[b];
            float v0 = 0.f, v1 = 0.f;
#pragma unroll
            for (int k = 0; k < KNB; k += 2) {
                v0 = fmaf(sw[b][k],     emb[(size_t)snb[b][k] * DIM + t],     v0);
                v1 = fmaf(sw[b][k + 1], emb[(size_t)snb[b][k + 1] * DIM + t], v1);
            }
            size_t idx = (size_t)hh * DIM + t;
            emb[idx] = c * (v0 + v1) + (1.f - c) * emb[idx];
        }
    }
}

// ------------------------------------------------------------------ decode
__global__ __launch_bounds__(256)
void decode_kernel(const float* __restrict__ emb, const int* __restrict__ head,
                   const int* __restrict__ rel, const int* __restrict__ tail,
                   const float* __restrict__ rel_emb, float* __restrict__ out) {
    int b = blockIdx.x, t = threadIdx.x;
    float v = emb[(size_t)head[b] * DIM + t] *
              rel_emb[(size_t)rel[b] * DIM + t] *
              emb[(size_t)tail[b] * DIM + t];
    __shared__ float red[4];
#pragma unroll
    for (int off = 32; off; off >>= 1) v += __shfl_down(v, off);
    int lane = t & 63, w = t >> 6;
    if (lane == 0) red[w] = v;
    __syncthreads();
    if (t == 0) {
        float s = red[0] + red[1] + red[2] + red[3];
        out[b] = 1.f / (1.f + expf(-s));
    }
}

// ------------------------------------------------------------------ launch
extern "C" void kernel_launch(void* const* d_in, const int* in_sizes, int n_in,
                              void* d_out, int out_size, void* d_ws, size_t ws_size,
                              hipStream_t stream) {
    const float* x        = (const float*)d_in[0];
    const int*   ei       = (const int*)d_in[1];
    const int*   head     = (const int*)d_in[2];
    const int*   rel      = (const int*)d_in[3];
    const int*   tail     = (const int*)d_in[4];
    const int*   g2l      = (const int*)d_in[5];
    const int*   res      = (const int*)d_in[6];
    const int*   nbs      = (const int*)d_in[7];
    const float* wts      = (const float*)d_in[8];
    const float* W1       = (const float*)d_in[9];
    const float* a1s      = (const float*)d_in[10];
    const float* a1d      = (const float*)d_in[11];
    const float* b1       = (const float*)d_in[12];
    const float* W2       = (const float*)d_in[13];
    const float* a2s      = (const float*)d_in[14];
    const float* a2d      = (const float*)d_in[15];
    const float* b2       = (const float*)d_in[16];
    const float* rel_emb  = (const float*)d_in[17];
    float* out = (float*)d_out;

    char* ws = (char*)d_ws;
    size_t off_b = 0;
    auto alloc = [&](size_t bytes) {
        void* pp = ws + off_b;
        off_b += (bytes + 255) & ~(size_t)255;
        return pp;
    };
    float*  bufB    = (float*)alloc((size_t)N_NODES * DIM * 4);  // layer-2 out (fp32)
    ushort* hb      = (ushort*)alloc((size_t)N_NODES * DIM * 2); // bf16 h rows (gemm out)
    ushort* h1b     = (ushort*)alloc((size_t)N_NODES * DIM * 2); // bf16 layer-1 out
    float*  hs      = (float*)alloc((size_t)N_NODES * 4);
    float*  hd      = (float*)alloc((size_t)N_NODES * 4);
    // ---- zeroed region (one fused memset) ----
    size_t z0 = off_b;
    int*    deg     = (int*)alloc((size_t)N_NODES * 4);
    int*    rhist   = (int*)alloc((size_t)3 * ND_ * 4);
    int*    flags   = (int*)alloc((size_t)BSZ * 4);
    size_t z1 = off_b;
    // ------------------------------------------
    int*    offs    = (int*)alloc((size_t)(N_NODES + 1) * 4);
    int*    csr_src = (int*)alloc((size_t)N_EDGES * 4);
    int*    bsum    = (int*)alloc((size_t)NB_SCAN * 4);
    int*    bpre    = (int*)alloc((size_t)NB_SCAN * 4);
    ushort* wpack1  = (ushort*)alloc((size_t)256 * 256 * 2);
    ushort* wpack2  = (ushort*)alloc((size_t)256 * 256 * 2);

    const int edgeBlocks = (N_EDGES + 255) / 256;
    const int gemmBlocks = MTILES_PAD / 4;   // 782
    const int nodeBlocks4 = (N_NODES + 3) / 4;

    // ---------------- CSR build + weight packs + rel histogram ----
    hipMemsetAsync(ws + z0, 0, z1 - z0, stream);   // deg + rhist + flags
    hist_kernel<<<edgeBlocks, 256, 0, stream>>>(ei, deg);
    blockscan_kernel<<<NB_SCAN, 256, 0, stream>>>(deg, offs, bsum);
    scan_bsum_kernel<<<1, 256, 0, stream>>>(bsum, bpre);
    add_offsets_kernel<<<NB_SCAN, 256, 0, stream>>>(offs, bpre);
    scatter_kernel<<<edgeBlocks, 256, 0, stream>>>(ei, offs, csr_src);
    pack_b_kernel<<<16, 256, 0, stream>>>(W1, wpack1);
    pack_b_kernel<<<16, 256, 0, stream>>>(W2, wpack2);
    rel_hist_kernel<<<(3 * ER_ + 255) / 256, 256, 0, stream>>>(res, rhist);

    // ---------------- layer 1 (A = x, fp32 direct) ----------------
    gemm_bf16_kernel<1><<<gemmBlocks, 256, 0, stream>>>(x, nullptr, wpack1, hb,
                                                        a1s, a1d, hs, hd, N_NODES);
    gat_aggr_kernel<<<nodeBlocks4, 256, 0, stream>>>(offs, csr_src, hs, hd, hb, b1,
                                                     nullptr, h1b, 1);

    // ---------------- layer 2 (A = h1b, bf16 direct) ----------------
    gemm_bf16_kernel<0><<<gemmBlocks, 256, 0, stream>>>(nullptr, h1b, wpack2, hb,
                                                        a2s, a2d, hs, hd, N_NODES);
    gat_aggr_kernel<<<nodeBlocks4, 256, 0, stream>>>(offs, csr_src, hs, hd, hb, b2,
                                                     bufB, nullptr, 0);

    // ---------------- scan (conflict -> fused apply) + decode ----------------
    conflict_kernel<<<BSZ, 256, 0, stream>>>(head, rel, g2l, nbs, flags);
    apply_kernel<<<BSZ + 1, 256, 0, stream>>>(bufB, head, rel, g2l, nbs, wts,
                                              rhist, flags);
    decode_kernel<<<BSZ, 256, 0, stream>>>(bufB, head, rel, tail, rel_emb, out);
}

// Round 10
// 397.773 us; speedup vs baseline: 1.1051x; 1.1051x over previous
//
#include <hip/hip_runtime.h>
#include <cstdint>

#define N_NODES 50000
#define N_EDGES 800000
#define DIM     256
#define BSZ     256
#define ND_     5000
#define KNB     16
#define ER_     20000
#define LAM     0.7f

typedef unsigned int uint;
typedef unsigned short ushort;
typedef __attribute__((ext_vector_type(8))) short bf16x8;
typedef __attribute__((ext_vector_type(4))) float f32x4;

#define NB_SCAN    ((N_NODES + 255) / 256)      // 196
#define GROWS      64                           // gemm tile rows
#define GEMM_BLKS  ((N_NODES + GROWS - 1) / GROWS)   // 782
#define RH_BLKS    ((3 * ER_ + 255) / 256)      // 235
#define HIST_BLKS  ((N_EDGES + 255) / 256)      // 3125

__device__ __forceinline__ ushort f2bf(float f) {
    uint u = __float_as_uint(f);
    uint r = u + 0x7FFFu + ((u >> 16) & 1u);   // round-to-nearest-even
    return (ushort)(r >> 16);
}
__device__ __forceinline__ float bflo(uint u) { return __uint_as_float(u << 16); }
__device__ __forceinline__ float bfhi(uint u) { return __uint_as_float(u & 0xffff0000u); }

// fragment k-map: elem j, lane-group lg -> kk=(j&3)+lg*4+(j>>2)*16, same
// bijection for A and B fragments (permutation cancels inside the MFMA dot).

// ---------------- pack W [K=256,N=256] f32 -> frag order (device body) ----
__device__ __forceinline__ void pack_b_body(const float* __restrict__ W,
                                            ushort* __restrict__ out, int nt, int t) {
    const int l  = t & 63;
    const int kt0 = (t >> 6) * 2;
    const int n  = nt * 16 + (l & 15);
    const int lg = l >> 4;
#pragma unroll
    for (int p = 0; p < 2; ++p) {
        int kt = kt0 + p;
        ushort us[8];
#pragma unroll
        for (int j = 0; j < 8; ++j) {
            int kk = (j & 3) + lg * 4 + (j >> 2) * 16;
            us[j] = f2bf(W[(size_t)(kt * 32 + kk) * 256 + n]);
        }
        *(uint4*)(out + ((size_t)(nt * 8 + kt) * 64 + l) * 8) = *(uint4*)us;
    }
}

// -------- merged prep: pack W1 | pack W2 | rel-hist | dst-degree hist -----
__global__ __launch_bounds__(256)
void prep_kernel(const float* __restrict__ W1, const float* __restrict__ W2,
                 ushort* __restrict__ wp1, ushort* __restrict__ wp2,
                 const int* __restrict__ res, int* __restrict__ rhist,
                 const int* __restrict__ ei, int* __restrict__ deg) {
    const int b = blockIdx.x, t = threadIdx.x;
    if (b < 16)       { pack_b_body(W1, wp1, b, t);      return; }
    if (b < 32)       { pack_b_body(W2, wp2, b - 16, t); return; }
    if (b < 32 + RH_BLKS) {
        int i = (b - 32) * 256 + t;
        if (i < 3 * ER_) atomicAdd(&rhist[(i / ER_) * ND_ + res[i]], 1);
        return;
    }
    int e = (b - 32 - RH_BLKS) * 256 + t;
    if (e < N_EDGES) atomicAdd(&deg[ei[N_EDGES + e]], 1);
}

// -------- LDS-staged bf16 MFMA GEMM + fused attention-dots epilogue -------
// H[M,256] (bf16 row-major) = A @ B ; hs/hd = H @ a_src / H @ a_dst
// A staged 64x256 per block, coalesced, XOR-swizzled chunks (c ^= row&15):
// both ds_write and fragment ds_read_b64 are bank-conflict-free.
template<int SRCF32>
__global__ __launch_bounds__(256)
void gemm_fused_kernel(const float* __restrict__ Af, const ushort* __restrict__ Ab,
                       const ushort* __restrict__ Bp, ushort* __restrict__ H,
                       const float* __restrict__ a_src, const float* __restrict__ a_dst,
                       float* __restrict__ hs, float* __restrict__ hd, int M) {
    __shared__ uint2 lda[GROWS * 64];        // chunk = 4 bf16 (8B); 32 KiB
    __shared__ float sdS[4][64];
    __shared__ float sdD[4][64];
    const int t = threadIdx.x;
    const int w = t >> 6;
    const int l = t & 63;
    const int rb = blockIdx.x * GROWS;

    // ---- stage A (coalesced) ----
    if (SRCF32) {
#pragma unroll
        for (int u = 0; u < 16; ++u) {
            int f = t + u * 256;              // float4 index; 64 per row
            int r = f >> 6;
            int cq = f & 63;                  // chunk (4 cols)
            int grow = rb + r;
            float4 v = (grow < M) ? *(const float4*)(Af + (size_t)grow * 256 + cq * 4)
                                  : make_float4(0.f, 0.f, 0.f, 0.f);
            uint2 o;
            o.x = (uint)f2bf(v.x) | ((uint)f2bf(v.y) << 16);
            o.y = (uint)f2bf(v.z) | ((uint)f2bf(v.w) << 16);
            lda[r * 64 + (cq ^ (r & 15))] = o;
        }
    } else {
#pragma unroll
        for (int u = 0; u < 8; ++u) {
            int f = t + u * 256;              // uint4 index; 32 per row
            int r = f >> 5;
            int p = f & 31;
            int grow = rb + r;
            uint4 v = (grow < M) ? *(const uint4*)(Ab + (size_t)grow * 256 + p * 8)
                                 : make_uint4(0u, 0u, 0u, 0u);
            int c = p * 2;
            lda[r * 64 + ( c      ^ (r & 15))] = make_uint2(v.x, v.y);
            lda[r * 64 + ((c + 1) ^ (r & 15))] = make_uint2(v.z, v.w);
        }
    }
    __syncthreads();

    // ---- MFMA ----
    const int cb = l & 15;
    const int lg = l >> 4;
    f32x4 acc[4][4];
#pragma unroll
    for (int i = 0; i < 4; ++i)
#pragma unroll
        for (int j = 0; j < 4; ++j) acc[i][j] = (f32x4){0.f, 0.f, 0.f, 0.f};

    for (int kt = 0; kt < 8; ++kt) {
        bf16x8 af[4], bfr[4];
#pragma unroll
        for (int mi = 0; mi < 4; ++mi) {
            int row = mi * 16 + cb;
            uint2 lo = lda[row * 64 + ((kt * 8 + lg)     ^ cb)];
            uint2 hi = lda[row * 64 + ((kt * 8 + lg + 4) ^ cb)];
            uint4 cmb; cmb.x = lo.x; cmb.y = lo.y; cmb.z = hi.x; cmb.w = hi.y;
            af[mi] = *(bf16x8*)&cmb;
        }
#pragma unroll
        for (int ni = 0; ni < 4; ++ni)
            bfr[ni] = *(const bf16x8*)(Bp + ((size_t)((w * 4 + ni) * 8 + kt) * 64 + l) * 8);
#pragma unroll
        for (int mi = 0; mi < 4; ++mi)
#pragma unroll
            for (int ni = 0; ni < 4; ++ni)
                acc[mi][ni] = __builtin_amdgcn_mfma_f32_16x16x32_bf16(
                    af[mi], bfr[ni], acc[mi][ni], 0, 0, 0);
    }

    // ---- epilogue: H store + fused dots (C/D: col=lane&15, row=(lane>>4)*4+reg) ----
    const int rbase = (l >> 4) * 4;
    float asv[4], adv[4];
#pragma unroll
    for (int ni = 0; ni < 4; ++ni) {
        int col = (w * 4 + ni) * 16 + cb;
        asv[ni] = a_src[col];
        adv[ni] = a_dst[col];
    }
#pragma unroll
    for (int mi = 0; mi < 4; ++mi) {
#pragma unroll
        for (int r = 0; r < 4; ++r) {
            int row = rb + mi * 16 + rbase + r;
            float ps = 0.f, pd = 0.f;
#pragma unroll
            for (int ni = 0; ni < 4; ++ni) {
                float hv = acc[mi][ni][r];
                ps = fmaf(hv, asv[ni], ps);
                pd = fmaf(hv, adv[ni], pd);
                if (row < M) {
                    int col = (w * 4 + ni) * 16 + cb;
                    H[(size_t)row * 256 + col] = f2bf(hv);
                }
            }
#pragma unroll
            for (int o = 1; o < 16; o <<= 1) {
                ps += __shfl_xor(ps, o);
                pd += __shfl_xor(pd, o);
            }
            if (cb == 0) {
                sdS[w][mi * 16 + rbase + r] = ps;
                sdD[w][mi * 16 + rbase + r] = pd;
            }
        }
    }
    __syncthreads();
    if (t < 64) {
        int row = rb + t;
        if (row < M) {
            hs[row] = sdS[0][t] + sdS[1][t] + sdS[2][t] + sdS[3][t];
            hd[row] = sdD[0][t] + sdD[1][t] + sdD[2][t] + sdD[3][t];
        }
    }
}

// -------- two-level parallel exclusive scan of deg -> offs --------
__global__ __launch_bounds__(256)
void blockscan_kernel(const int* __restrict__ deg, int* __restrict__ off,
                      int* __restrict__ bsum) {
    __shared__ int s[256];
    const int b = blockIdx.x, t = threadIdx.x;
    const int idx = b * 256 + t;
    int v = (idx < N_NODES) ? deg[idx] : 0;
    s[t] = v;
    __syncthreads();
    for (int o = 1; o < 256; o <<= 1) {
        int x = (t >= o) ? s[t - o] : 0;
        __syncthreads();
        s[t] += x;
        __syncthreads();
    }
    if (idx < N_NODES) off[idx] = s[t] - v;
    if (t == 255) bsum[b] = s[255];
}

__global__ __launch_bounds__(256)
void scan_bsum_kernel(const int* __restrict__ bsum, int* __restrict__ bpre) {
    __shared__ int s[256];
    const int t = threadIdx.x;
    int v = (t < NB_SCAN) ? bsum[t] : 0;
    s[t] = v;
    __syncthreads();
    for (int o = 1; o < 256; o <<= 1) {
        int x = (t >= o) ? s[t - o] : 0;
        __syncthreads();
        s[t] += x;
        __syncthreads();
    }
    if (t < NB_SCAN) bpre[t] = s[t] - v;
    if (t == 255) bpre[NB_SCAN] = s[255];
}

__global__ __launch_bounds__(256)
void add_offsets_kernel(int* __restrict__ off, const int* __restrict__ bpre) {
    const int b = blockIdx.x, t = threadIdx.x;
    const int idx = b * 256 + t;
    if (idx < N_NODES) off[idx] += bpre[b];
    if (b == NB_SCAN - 1 && t == 255) off[N_NODES] = bpre[NB_SCAN];
}

// cnt-based scatter (offs left intact -> rocprof replay-safe)
__global__ __launch_bounds__(256)
void scatter_kernel(const int* __restrict__ ei, const int* __restrict__ off,
                    int* __restrict__ cnt, int* __restrict__ csr_src) {
    int e = blockIdx.x * 256 + threadIdx.x;
    if (e >= N_EDGES) return;
    int d = ei[N_EDGES + e];
    int pos = atomicAdd(&cnt[d], 1);
    csr_src[off[d] + pos] = ei[e];
}

// ----------------- fused GAT edge stage: wave-per-dst, no max, no barriers
// 4x-unrolled gather for memory-level parallelism (round-8 proven form).
__global__ __launch_bounds__(256)
void gat_aggr_kernel(const int* __restrict__ off, const int* __restrict__ csr_src,
                     const float* __restrict__ hs, const float* __restrict__ hd,
                     const ushort* __restrict__ hb, const float* __restrict__ bias,
                     float* __restrict__ out_f32, ushort* __restrict__ out_bf,
                     int do_silu) {
    const int d = blockIdx.x * 4 + (threadIdx.x >> 6);
    const int l = threadIdx.x & 63;
    if (d >= N_NODES) return;
    const int beg = off[d], end = off[d + 1];
    const float hdd = hd[d];

    float acc0 = 0.f, acc1 = 0.f, acc2 = 0.f, acc3 = 0.f;
    float zl = 0.f;
    const ushort* __restrict__ hcol = hb + l * 4;

    for (int c0 = beg; c0 < end; c0 += 64) {
        const int cn = min(end - c0, 64);
        int s = 0; float pexp = 0.f;
        if (l < cn) {
            s = csr_src[c0 + l];
            float v = hs[s] + hdd;
            v = (v >= 0.f) ? v : 0.2f * v;
            pexp = __expf(v);
        }
        zl += pexp;
        int j = 0;
        for (; j + 4 <= cn; j += 4) {
            int   s0 = __shfl(s, j),     s1 = __shfl(s, j + 1);
            int   s2 = __shfl(s, j + 2), s3 = __shfl(s, j + 3);
            float p0 = __shfl(pexp, j),     p1 = __shfl(pexp, j + 1);
            float p2 = __shfl(pexp, j + 2), p3 = __shfl(pexp, j + 3);
            uint2 r0 = *(const uint2*)(hcol + (size_t)s0 * DIM);
            uint2 r1 = *(const uint2*)(hcol + (size_t)s1 * DIM);
            uint2 r2 = *(const uint2*)(hcol + (size_t)s2 * DIM);
            uint2 r3 = *(const uint2*)(hcol + (size_t)s3 * DIM);
            acc0 = fmaf(p0, bflo(r0.x), acc0); acc1 = fmaf(p0, bfhi(r0.x), acc1);
            acc2 = fmaf(p0, bflo(r0.y), acc2); acc3 = fmaf(p0, bfhi(r0.y), acc3);
            acc0 = fmaf(p1, bflo(r1.x), acc0); acc1 = fmaf(p1, bfhi(r1.x), acc1);
            acc2 = fmaf(p1, bflo(r1.y), acc2); acc3 = fmaf(p1, bfhi(r1.y), acc3);
            acc0 = fmaf(p2, bflo(r2.x), acc0); acc1 = fmaf(p2, bfhi(r2.x), acc1);
            acc2 = fmaf(p2, bflo(r2.y), acc2); acc3 = fmaf(p2, bfhi(r2.y), acc3);
            acc0 = fmaf(p3, bflo(r3.x), acc0); acc1 = fmaf(p3, bfhi(r3.x), acc1);
            acc2 = fmaf(p3, bflo(r3.y), acc2); acc3 = fmaf(p3, bfhi(r3.y), acc3);
        }
        for (; j < cn; ++j) {
            int   sj = __shfl(s, j);
            float pj = __shfl(pexp, j);
            uint2 rv = *(const uint2*)(hcol + (size_t)sj * DIM);
            acc0 = fmaf(pj, bflo(rv.x), acc0); acc1 = fmaf(pj, bfhi(rv.x), acc1);
            acc2 = fmaf(pj, bflo(rv.y), acc2); acc3 = fmaf(pj, bfhi(rv.y), acc3);
        }
    }
    float z = zl;
#pragma unroll
    for (int o = 32; o; o >>= 1) z += __shfl_xor(z, o);
    const float inv = (end > beg) ? 1.f / (z + 1e-16f) : 0.f;
    float4 bb = *(const float4*)(bias + l * 4);
    float o0 = acc0 * inv + bb.x;
    float o1 = acc1 * inv + bb.y;
    float o2 = acc2 * inv + bb.z;
    float o3 = acc3 * inv + bb.w;
    if (do_silu) {
        o0 = o0 / (1.f + __expf(-o0));
        o1 = o1 / (1.f + __expf(-o1));
        o2 = o2 / (1.f + __expf(-o2));
        o3 = o3 / (1.f + __expf(-o3));
    }
    if (out_bf) {
        ushort us[4] = {f2bf(o0), f2bf(o1), f2bf(o2), f2bf(o3)};
        *(uint2*)(out_bf + (size_t)d * DIM + l * 4) = *(uint2*)us;
    } else {
        *(float4*)(out_f32 + (size_t)d * DIM + l * 4) = make_float4(o0, o1, o2, o3);
    }
}

// ----------- conflict detection (flags pre-zeroed by the fused memset).
__global__ __launch_bounds__(256)
void conflict_kernel(const int* __restrict__ head, const int* __restrict__ rel,
                     const int* __restrict__ g2l, const int* __restrict__ nbs,
                     int* __restrict__ flags) {
    int b = blockIdx.x;
    int rb = rel[b];
    if (rb < 4 || rb > 6) return;
    __shared__ int rd[KNB + 1];
    int t = threadIdx.x;
    if (t == 0) rd[KNB] = head[b];
    if (t < KNB) rd[t] = nbs[(size_t)g2l[head[b]] * KNB + t];
    __syncthreads();
    int rt = rel[t];
    int w = (t != b && rt >= 4 && rt <= 6) ? head[t] : -1;
    if (w >= 0) {
        bool hit = false;
#pragma unroll
        for (int k = 0; k <= KNB; ++k) hit |= (rd[k] == w);
        if (hit) { flags[b] = 1; flags[t] = 1; }
    }
}

// ----------- fused apply: blocks 0..255 = independent steps (rows untouched
// by any other step); block 256 = flagged steps in program order (each thread
// owns one column -> no barriers in the walk). Par/seq rows disjoint.
__global__ __launch_bounds__(256)
void apply_kernel(float* __restrict__ emb, const int* __restrict__ head,
                  const int* __restrict__ rel, const int* __restrict__ g2l,
                  const int* __restrict__ nbs, const float* __restrict__ wts,
                  const int* __restrict__ rhist, const int* __restrict__ flags) {
    const int t = threadIdx.x;
    if (blockIdx.x < BSZ) {
        int b = blockIdx.x;
        int r = rel[b];
        if (r < 4 || r > 6) return;
        if (flags[b]) return;
        int hi = head[b];
        int local = g2l[hi];
        int dg = rhist[(r - 4) * ND_ + local];
        float c = LAM * __expf(-LAM * (float)dg) + 0.2f;
        const int* __restrict__ nb = nbs + (size_t)local * KNB;
        const float* __restrict__ w = wts + (size_t)local * KNB;
        float v0 = 0.f, v1 = 0.f;
#pragma unroll
        for (int k = 0; k < KNB; k += 2) {
            v0 = fmaf(w[k],     emb[(size_t)nb[k] * DIM + t],     v0);
            v1 = fmaf(w[k + 1], emb[(size_t)nb[k + 1] * DIM + t], v1);
        }
        size_t idx = (size_t)hi * DIM + t;
        emb[idx] = c * (v0 + v1) + (1.f - c) * emb[idx];
        return;
    }
    // ---- sequential block ----
    __shared__ int   snb[BSZ][KNB];
    __shared__ float sw[BSZ][KNB];
    __shared__ int   sh[BSZ];
    __shared__ float sc[BSZ];
    __shared__ int   sf[BSZ];
    int r = rel[t];
    int dis = (r >= 4 && r <= 6);
    int hi = head[t];
    sh[t] = hi;
    sf[t] = dis ? flags[t] : 0;
    if (dis) {
        int local = g2l[hi];
        int dg = rhist[(r - 4) * ND_ + local];
        sc[t] = LAM * __expf(-LAM * (float)dg) + 0.2f;
#pragma unroll
        for (int k = 0; k < KNB; ++k) {
            snb[t][k] = nbs[(size_t)local * KNB + k];
            sw[t][k]  = wts[(size_t)local * KNB + k];
        }
    }
    __syncthreads();
    for (int b = 0; b < BSZ; ++b) {
        if (sf[b]) {
            int hh = sh[b];
            float c = sc[b];
            float v0 = 0.f, v1 = 0.f;
#pragma unroll
            for (int k = 0; k < KNB; k += 2) {
                v0 = fmaf(sw[b][k],     emb[(size_t)snb[b][k] * DIM + t],     v0);
                v1 = fmaf(sw[b][k + 1], emb[(size_t)snb[b][k + 1] * DIM + t], v1);
            }
            size_t idx = (size_t)hh * DIM + t;
            emb[idx] = c * (v0 + v1) + (1.f - c) * emb[idx];
        }
    }
}

// ------------------------------------------------------------------ decode
__global__ __launch_bounds__(256)
void decode_kernel(const float* __restrict__ emb, const int* __restrict__ head,
                   const int* __restrict__ rel, const int* __restrict__ tail,
                   const float* __restrict__ rel_emb, float* __restrict__ out) {
    int b = blockIdx.x, t = threadIdx.x;
    float v = emb[(size_t)head[b] * DIM + t] *
              rel_emb[(size_t)rel[b] * DIM + t] *
              emb[(size_t)tail[b] * DIM + t];
    __shared__ float red[4];
#pragma unroll
    for (int off = 32; off; off >>= 1) v += __shfl_down(v, off);
    int lane = t & 63, w = t >> 6;
    if (lane == 0) red[w] = v;
    __syncthreads();
    if (t == 0) {
        float s = red[0] + red[1] + red[2] + red[3];
        out[b] = 1.f / (1.f + expf(-s));
    }
}

// ------------------------------------------------------------------ launch
extern "C" void kernel_launch(void* const* d_in, const int* in_sizes, int n_in,
                              void* d_out, int out_size, void* d_ws, size_t ws_size,
                              hipStream_t stream) {
    const float* x        = (const float*)d_in[0];
    const int*   ei       = (const int*)d_in[1];
    const int*   head     = (const int*)d_in[2];
    const int*   rel      = (const int*)d_in[3];
    const int*   tail     = (const int*)d_in[4];
    const int*   g2l      = (const int*)d_in[5];
    const int*   res      = (const int*)d_in[6];
    const int*   nbs      = (const int*)d_in[7];
    const float* wts      = (const float*)d_in[8];
    const float* W1       = (const float*)d_in[9];
    const float* a1s      = (const float*)d_in[10];
    const float* a1d      = (const float*)d_in[11];
    const float* b1       = (const float*)d_in[12];
    const float* W2       = (const float*)d_in[13];
    const float* a2s      = (const float*)d_in[14];
    const float* a2d      = (const float*)d_in[15];
    const float* b2       = (const float*)d_in[16];
    const float* rel_emb  = (const float*)d_in[17];
    float* out = (float*)d_out;

    char* ws = (char*)d_ws;
    size_t off_b = 0;
    auto alloc = [&](size_t bytes) {
        void* pp = ws + off_b;
        off_b += (bytes + 255) & ~(size_t)255;
        return pp;
    };
    float*  bufB    = (float*)alloc((size_t)N_NODES * DIM * 4);  // layer-2 out (fp32)
    ushort* hb      = (ushort*)alloc((size_t)N_NODES * DIM * 2); // bf16 h rows (gemm out)
    ushort* h1b     = (ushort*)alloc((size_t)N_NODES * DIM * 2); // bf16 layer-1 out
    float*  hs      = (float*)alloc((size_t)N_NODES * 4);
    float*  hd      = (float*)alloc((size_t)N_NODES * 4);
    // ---- zeroed region (one fused memset) ----
    size_t z0 = off_b;
    int*    deg     = (int*)alloc((size_t)N_NODES * 4);
    int*    cnt     = (int*)alloc((size_t)N_NODES * 4);
    int*    rhist   = (int*)alloc((size_t)3 * ND_ * 4);
    int*    flags   = (int*)alloc((size_t)BSZ * 4);
    size_t z1 = off_b;
    // ------------------------------------------
    int*    offs    = (int*)alloc((size_t)(N_NODES + 1) * 4);
    int*    csr_src = (int*)alloc((size_t)N_EDGES * 4);
    int*    bsum    = (int*)alloc((size_t)NB_SCAN * 4);
    int*    bpre    = (int*)alloc((size_t)(NB_SCAN + 1) * 4);
    ushort* wpack1  = (ushort*)alloc((size_t)256 * 256 * 2);
    ushort* wpack2  = (ushort*)alloc((size_t)256 * 256 * 2);

    const int nodeBlocks4 = (N_NODES + 3) / 4;
    const int prepBlocks  = 32 + RH_BLKS + HIST_BLKS;

    // ---------------- prep: memset + {packW1|packW2|rel_hist|hist} ----------
    hipMemsetAsync(ws + z0, 0, z1 - z0, stream);   // deg + cnt + rhist + flags
    prep_kernel<<<prepBlocks, 256, 0, stream>>>(W1, W2, wpack1, wpack2,
                                                res, rhist, ei, deg);
    blockscan_kernel<<<NB_SCAN, 256, 0, stream>>>(deg, offs, bsum);
    scan_bsum_kernel<<<1, 256, 0, stream>>>(bsum, bpre);
    add_offsets_kernel<<<NB_SCAN, 256, 0, stream>>>(offs, bpre);
    scatter_kernel<<<HIST_BLKS, 256, 0, stream>>>(ei, offs, cnt, csr_src);

    // ---------------- layer 1 (A = x, fp32, staged in LDS) ----------------
    gemm_fused_kernel<1><<<GEMM_BLKS, 256, 0, stream>>>(x, nullptr, wpack1, hb,
                                                        a1s, a1d, hs, hd, N_NODES);
    gat_aggr_kernel<<<nodeBlocks4, 256, 0, stream>>>(offs, csr_src, hs, hd, hb, b1,
                                                     nullptr, h1b, 1);

    // ---------------- layer 2 (A = h1b, bf16, staged in LDS) ----------------
    gemm_fused_kernel<0><<<GEMM_BLKS, 256, 0, stream>>>(nullptr, h1b, wpack2, hb,
                                                        a2s, a2d, hs, hd, N_NODES);
    gat_aggr_kernel<<<nodeBlocks4, 256, 0, stream>>>(offs, csr_src, hs, hd, hb, b2,
                                                     bufB, nullptr, 0);

    // ---------------- scan (conflict -> fused apply) + decode ----------------
    conflict_kernel<<<BSZ, 256, 0, stream>>>(head, rel, g2l, nbs, flags);
    apply_kernel<<<BSZ + 1, 256, 0, stream>>>(bufB, head, rel, g2l, nbs, wts,
                                              rhist, flags);
    decode_kernel<<<BSZ, 256, 0, stream>>>(bufB, head, rel, tail, rel_emb, out);
}

// Round 11
// 392.901 us; speedup vs baseline: 1.1188x; 1.0124x over previous
//
#include <hip/hip_runtime.h>
#include <cstdint>

#define N_NODES 50000
#define N_EDGES 800000
#define DIM     256
#define BSZ     256
#define ND_     5000
#define KNB     16
#define ER_     20000
#define LAM     0.7f

typedef unsigned int uint;
typedef unsigned short ushort;
typedef __attribute__((ext_vector_type(8))) short bf16x8;
typedef __attribute__((ext_vector_type(4))) float f32x4;

#define NB_SCAN    ((N_NODES + 255) / 256)      // 196
#define GROWS      64                           // gemm tile rows
#define GEMM_BLKS  ((N_NODES + GROWS - 1) / GROWS)   // 782
#define RH_BLKS    ((3 * ER_ + 255) / 256)      // 235
#define HIST_BLKS  ((N_EDGES + 255) / 256)      // 3125

__device__ __forceinline__ ushort f2bf(float f) {
    uint u = __float_as_uint(f);
    uint r = u + 0x7FFFu + ((u >> 16) & 1u);   // round-to-nearest-even
    return (ushort)(r >> 16);
}
__device__ __forceinline__ float bflo(uint u) { return __uint_as_float(u << 16); }
__device__ __forceinline__ float bfhi(uint u) { return __uint_as_float(u & 0xffff0000u); }

// fragment k-map: elem j, lane-group lg -> kk=(j&3)+lg*4+(j>>2)*16, same
// bijection for A and B fragments (permutation cancels inside the MFMA dot).

// ---------------- pack W [K=256,N=256] f32 -> frag order (device body) ----
__device__ __forceinline__ void pack_b_body(const float* __restrict__ W,
                                            ushort* __restrict__ out, int nt, int t) {
    const int l  = t & 63;
    const int kt0 = (t >> 6) * 2;
    const int n  = nt * 16 + (l & 15);
    const int lg = l >> 4;
#pragma unroll
    for (int p = 0; p < 2; ++p) {
        int kt = kt0 + p;
        ushort us[8];
#pragma unroll
        for (int j = 0; j < 8; ++j) {
            int kk = (j & 3) + lg * 4 + (j >> 2) * 16;
            us[j] = f2bf(W[(size_t)(kt * 32 + kk) * 256 + n]);
        }
        *(uint4*)(out + ((size_t)(nt * 8 + kt) * 64 + l) * 8) = *(uint4*)us;
    }
}

// -------- merged prep: pack W1 | pack W2 | rel-hist | dst-degree hist -----
__global__ __launch_bounds__(256)
void prep_kernel(const float* __restrict__ W1, const float* __restrict__ W2,
                 ushort* __restrict__ wp1, ushort* __restrict__ wp2,
                 const int* __restrict__ res, int* __restrict__ rhist,
                 const int* __restrict__ ei, int* __restrict__ deg) {
    const int b = blockIdx.x, t = threadIdx.x;
    if (b < 16)       { pack_b_body(W1, wp1, b, t);      return; }
    if (b < 32)       { pack_b_body(W2, wp2, b - 16, t); return; }
    if (b < 32 + RH_BLKS) {
        int i = (b - 32) * 256 + t;
        if (i < 3 * ER_) atomicAdd(&rhist[(i / ER_) * ND_ + res[i]], 1);
        return;
    }
    int e = (b - 32 - RH_BLKS) * 256 + t;
    if (e < N_EDGES) atomicAdd(&deg[ei[N_EDGES + e]], 1);
}

// -------- LDS-staged bf16 MFMA GEMM + fused attention-dots epilogue -------
// H[M,256] (bf16 row-major) = A @ B ; hs/hd = H @ a_src / H @ a_dst
// A staged 64x256 per block, coalesced, XOR-swizzled chunks (c ^= row&15):
// both ds_write and fragment ds_read_b64 are bank-conflict-free.
template<int SRCF32>
__global__ __launch_bounds__(256)
void gemm_fused_kernel(const float* __restrict__ Af, const ushort* __restrict__ Ab,
                       const ushort* __restrict__ Bp, ushort* __restrict__ H,
                       const float* __restrict__ a_src, const float* __restrict__ a_dst,
                       float* __restrict__ hs, float* __restrict__ hd, int M) {
    __shared__ uint2 lda[GROWS * 64];        // chunk = 4 bf16 (8B); 32 KiB
    __shared__ float sdS[4][64];
    __shared__ float sdD[4][64];
    const int t = threadIdx.x;
    const int w = t >> 6;
    const int l = t & 63;
    const int rb = blockIdx.x * GROWS;

    // ---- stage A (coalesced) ----
    if (SRCF32) {
#pragma unroll
        for (int u = 0; u < 16; ++u) {
            int f = t + u * 256;              // float4 index; 64 per row
            int r = f >> 6;
            int cq = f & 63;                  // chunk (4 cols)
            int grow = rb + r;
            float4 v = (grow < M) ? *(const float4*)(Af + (size_t)grow * 256 + cq * 4)
                                  : make_float4(0.f, 0.f, 0.f, 0.f);
            uint2 o;
            o.x = (uint)f2bf(v.x) | ((uint)f2bf(v.y) << 16);
            o.y = (uint)f2bf(v.z) | ((uint)f2bf(v.w) << 16);
            lda[r * 64 + (cq ^ (r & 15))] = o;
        }
    } else {
#pragma unroll
        for (int u = 0; u < 8; ++u) {
            int f = t + u * 256;              // uint4 index; 32 per row
            int r = f >> 5;
            int p = f & 31;
            int grow = rb + r;
            uint4 v = (grow < M) ? *(const uint4*)(Ab + (size_t)grow * 256 + p * 8)
                                 : make_uint4(0u, 0u, 0u, 0u);
            int c = p * 2;
            lda[r * 64 + ( c      ^ (r & 15))] = make_uint2(v.x, v.y);
            lda[r * 64 + ((c + 1) ^ (r & 15))] = make_uint2(v.z, v.w);
        }
    }
    __syncthreads();

    // ---- MFMA ----
    const int cb = l & 15;
    const int lg = l >> 4;
    f32x4 acc[4][4];
#pragma unroll
    for (int i = 0; i < 4; ++i)
#pragma unroll
        for (int j = 0; j < 4; ++j) acc[i][j] = (f32x4){0.f, 0.f, 0.f, 0.f};

    for (int kt = 0; kt < 8; ++kt) {
        bf16x8 af[4], bfr[4];
#pragma unroll
        for (int mi = 0; mi < 4; ++mi) {
            int row = mi * 16 + cb;
            uint2 lo = lda[row * 64 + ((kt * 8 + lg)     ^ cb)];
            uint2 hi = lda[row * 64 + ((kt * 8 + lg + 4) ^ cb)];
            uint4 cmb; cmb.x = lo.x; cmb.y = lo.y; cmb.z = hi.x; cmb.w = hi.y;
            af[mi] = *(bf16x8*)&cmb;
        }
#pragma unroll
        for (int ni = 0; ni < 4; ++ni)
            bfr[ni] = *(const bf16x8*)(Bp + ((size_t)((w * 4 + ni) * 8 + kt) * 64 + l) * 8);
#pragma unroll
        for (int mi = 0; mi < 4; ++mi)
#pragma unroll
            for (int ni = 0; ni < 4; ++ni)
                acc[mi][ni] = __builtin_amdgcn_mfma_f32_16x16x32_bf16(
                    af[mi], bfr[ni], acc[mi][ni], 0, 0, 0);
    }

    // ---- epilogue: H store + fused dots (C/D: col=lane&15, row=(lane>>4)*4+reg) ----
    const int rbase = (l >> 4) * 4;
    float asv[4], adv[4];
#pragma unroll
    for (int ni = 0; ni < 4; ++ni) {
        int col = (w * 4 + ni) * 16 + cb;
        asv[ni] = a_src[col];
        adv[ni] = a_dst[col];
    }
#pragma unroll
    for (int mi = 0; mi < 4; ++mi) {
#pragma unroll
        for (int r = 0; r < 4; ++r) {
            int row = rb + mi * 16 + rbase + r;
            float ps = 0.f, pd = 0.f;
#pragma unroll
            for (int ni = 0; ni < 4; ++ni) {
                float hv = acc[mi][ni][r];
                ps = fmaf(hv, asv[ni], ps);
                pd = fmaf(hv, adv[ni], pd);
                if (row < M) {
                    int col = (w * 4 + ni) * 16 + cb;
                    H[(size_t)row * 256 + col] = f2bf(hv);
                }
            }
#pragma unroll
            for (int o = 1; o < 16; o <<= 1) {
                ps += __shfl_xor(ps, o);
                pd += __shfl_xor(pd, o);
            }
            if (cb == 0) {
                sdS[w][mi * 16 + rbase + r] = ps;
                sdD[w][mi * 16 + rbase + r] = pd;
            }
        }
    }
    __syncthreads();
    if (t < 64) {
        int row = rb + t;
        if (row < M) {
            hs[row] = sdS[0][t] + sdS[1][t] + sdS[2][t] + sdS[3][t];
            hd[row] = sdD[0][t] + sdD[1][t] + sdD[2][t] + sdD[3][t];
        }
    }
}

// -------- two-level parallel exclusive scan of deg -> offs --------
__global__ __launch_bounds__(256)
void blockscan_kernel(const int* __restrict__ deg, int* __restrict__ off,
                      int* __restrict__ bsum) {
    __shared__ int s[256];
    const int b = blockIdx.x, t = threadIdx.x;
    const int idx = b * 256 + t;
    int v = (idx < N_NODES) ? deg[idx] : 0;
    s[t] = v;
    __syncthreads();
    for (int o = 1; o < 256; o <<= 1) {
        int x = (t >= o) ? s[t - o] : 0;
        __syncthreads();
        s[t] += x;
        __syncthreads();
    }
    if (idx < N_NODES) off[idx] = s[t] - v;
    if (t == 255) bsum[b] = s[255];
}

__global__ __launch_bounds__(256)
void scan_bsum_kernel(const int* __restrict__ bsum, int* __restrict__ bpre) {
    __shared__ int s[256];
    const int t = threadIdx.x;
    int v = (t < NB_SCAN) ? bsum[t] : 0;
    s[t] = v;
    __syncthreads();
    for (int o = 1; o < 256; o <<= 1) {
        int x = (t >= o) ? s[t - o] : 0;
        __syncthreads();
        s[t] += x;
        __syncthreads();
    }
    if (t < NB_SCAN) bpre[t] = s[t] - v;
    if (t == 255) bpre[NB_SCAN] = s[255];
}

__global__ __launch_bounds__(256)
void add_offsets_kernel(int* __restrict__ off, const int* __restrict__ bpre) {
    const int b = blockIdx.x, t = threadIdx.x;
    const int idx = b * 256 + t;
    if (idx < N_NODES) off[idx] += bpre[b];
    if (b == NB_SCAN - 1 && t == 255) off[N_NODES] = bpre[NB_SCAN];
}

// cnt-based scatter (offs left intact -> rocprof replay-safe)
__global__ __launch_bounds__(256)
void scatter_kernel(const int* __restrict__ ei, const int* __restrict__ off,
                    int* __restrict__ cnt, int* __restrict__ csr_src) {
    int e = blockIdx.x * 256 + threadIdx.x;
    if (e >= N_EDGES) return;
    int d = ei[N_EDGES + e];
    int pos = atomicAdd(&cnt[d], 1);
    csr_src[off[d] + pos] = ei[e];
}

// ----------------- fused GAT edge stage: wave-per-dst, no max, no barriers
// 8x-unrolled gather: 8 independent row loads in flight per latency wait.
__global__ __launch_bounds__(256)
void gat_aggr_kernel(const int* __restrict__ off, const int* __restrict__ csr_src,
                     const float* __restrict__ hs, const float* __restrict__ hd,
                     const ushort* __restrict__ hb, const float* __restrict__ bias,
                     float* __restrict__ out_f32, ushort* __restrict__ out_bf,
                     int do_silu) {
    const int d = blockIdx.x * 4 + (threadIdx.x >> 6);
    const int l = threadIdx.x & 63;
    if (d >= N_NODES) return;
    const int beg = off[d], end = off[d + 1];
    const float hdd = hd[d];

    float acc0 = 0.f, acc1 = 0.f, acc2 = 0.f, acc3 = 0.f;
    float zl = 0.f;
    const ushort* __restrict__ hcol = hb + l * 4;

    for (int c0 = beg; c0 < end; c0 += 64) {
        const int cn = min(end - c0, 64);
        int s = 0; float pexp = 0.f;
        if (l < cn) {
            s = csr_src[c0 + l];
            float v = hs[s] + hdd;
            v = (v >= 0.f) ? v : 0.2f * v;
            pexp = __expf(v);
        }
        zl += pexp;
        int j = 0;
        for (; j + 8 <= cn; j += 8) {
            int   s0 = __shfl(s, j),     s1 = __shfl(s, j + 1);
            int   s2 = __shfl(s, j + 2), s3 = __shfl(s, j + 3);
            int   s4 = __shfl(s, j + 4), s5 = __shfl(s, j + 5);
            int   s6 = __shfl(s, j + 6), s7 = __shfl(s, j + 7);
            float p0 = __shfl(pexp, j),     p1 = __shfl(pexp, j + 1);
            float p2 = __shfl(pexp, j + 2), p3 = __shfl(pexp, j + 3);
            float p4 = __shfl(pexp, j + 4), p5 = __shfl(pexp, j + 5);
            float p6 = __shfl(pexp, j + 6), p7 = __shfl(pexp, j + 7);
            uint2 r0 = *(const uint2*)(hcol + (size_t)s0 * DIM);
            uint2 r1 = *(const uint2*)(hcol + (size_t)s1 * DIM);
            uint2 r2 = *(const uint2*)(hcol + (size_t)s2 * DIM);
            uint2 r3 = *(const uint2*)(hcol + (size_t)s3 * DIM);
            uint2 r4 = *(const uint2*)(hcol + (size_t)s4 * DIM);
            uint2 r5 = *(const uint2*)(hcol + (size_t)s5 * DIM);
            uint2 r6 = *(const uint2*)(hcol + (size_t)s6 * DIM);
            uint2 r7 = *(const uint2*)(hcol + (size_t)s7 * DIM);
            acc0 = fmaf(p0, bflo(r0.x), acc0); acc1 = fmaf(p0, bfhi(r0.x), acc1);
            acc2 = fmaf(p0, bflo(r0.y), acc2); acc3 = fmaf(p0, bfhi(r0.y), acc3);
            acc0 = fmaf(p1, bflo(r1.x), acc0); acc1 = fmaf(p1, bfhi(r1.x), acc1);
            acc2 = fmaf(p1, bflo(r1.y), acc2); acc3 = fmaf(p1, bfhi(r1.y), acc3);
            acc0 = fmaf(p2, bflo(r2.x), acc0); acc1 = fmaf(p2, bfhi(r2.x), acc1);
            acc2 = fmaf(p2, bflo(r2.y), acc2); acc3 = fmaf(p2, bfhi(r2.y), acc3);
            acc0 = fmaf(p3, bflo(r3.x), acc0); acc1 = fmaf(p3, bfhi(r3.x), acc1);
            acc2 = fmaf(p3, bflo(r3.y), acc2); acc3 = fmaf(p3, bfhi(r3.y), acc3);
            acc0 = fmaf(p4, bflo(r4.x), acc0); acc1 = fmaf(p4, bfhi(r4.x), acc1);
            acc2 = fmaf(p4, bflo(r4.y), acc2); acc3 = fmaf(p4, bfhi(r4.y), acc3);
            acc0 = fmaf(p5, bflo(r5.x), acc0); acc1 = fmaf(p5, bfhi(r5.x), acc1);
            acc2 = fmaf(p5, bflo(r5.y), acc2); acc3 = fmaf(p5, bfhi(r5.y), acc3);
            acc0 = fmaf(p6, bflo(r6.x), acc0); acc1 = fmaf(p6, bfhi(r6.x), acc1);
            acc2 = fmaf(p6, bflo(r6.y), acc2); acc3 = fmaf(p6, bfhi(r6.y), acc3);
            acc0 = fmaf(p7, bflo(r7.x), acc0); acc1 = fmaf(p7, bfhi(r7.x), acc1);
            acc2 = fmaf(p7, bflo(r7.y), acc2); acc3 = fmaf(p7, bfhi(r7.y), acc3);
        }
        for (; j + 4 <= cn; j += 4) {
            int   s0 = __shfl(s, j),     s1 = __shfl(s, j + 1);
            int   s2 = __shfl(s, j + 2), s3 = __shfl(s, j + 3);
            float p0 = __shfl(pexp, j),     p1 = __shfl(pexp, j + 1);
            float p2 = __shfl(pexp, j + 2), p3 = __shfl(pexp, j + 3);
            uint2 r0 = *(const uint2*)(hcol + (size_t)s0 * DIM);
            uint2 r1 = *(const uint2*)(hcol + (size_t)s1 * DIM);
            uint2 r2 = *(const uint2*)(hcol + (size_t)s2 * DIM);
            uint2 r3 = *(const uint2*)(hcol + (size_t)s3 * DIM);
            acc0 = fmaf(p0, bflo(r0.x), acc0); acc1 = fmaf(p0, bfhi(r0.x), acc1);
            acc2 = fmaf(p0, bflo(r0.y), acc2); acc3 = fmaf(p0, bfhi(r0.y), acc3);
            acc0 = fmaf(p1, bflo(r1.x), acc0); acc1 = fmaf(p1, bfhi(r1.x), acc1);
            acc2 = fmaf(p1, bflo(r1.y), acc2); acc3 = fmaf(p1, bfhi(r1.y), acc3);
            acc0 = fmaf(p2, bflo(r2.x), acc0); acc1 = fmaf(p2, bfhi(r2.x), acc1);
            acc2 = fmaf(p2, bflo(r2.y), acc2); acc3 = fmaf(p2, bfhi(r2.y), acc3);
            acc0 = fmaf(p3, bflo(r3.x), acc0); acc1 = fmaf(p3, bfhi(r3.x), acc1);
            acc2 = fmaf(p3, bflo(r3.y), acc2); acc3 = fmaf(p3, bfhi(r3.y), acc3);
        }
        for (; j < cn; ++j) {
            int   sj = __shfl(s, j);
            float pj = __shfl(pexp, j);
            uint2 rv = *(const uint2*)(hcol + (size_t)sj * DIM);
            acc0 = fmaf(pj, bflo(rv.x), acc0); acc1 = fmaf(pj, bfhi(rv.x), acc1);
            acc2 = fmaf(pj, bflo(rv.y), acc2); acc3 = fmaf(pj, bfhi(rv.y), acc3);
        }
    }
    float z = zl;
#pragma unroll
    for (int o = 32; o; o >>= 1) z += __shfl_xor(z, o);
    const float inv = (end > beg) ? 1.f / (z + 1e-16f) : 0.f;
    float4 bb = *(const float4*)(bias + l * 4);
    float o0 = acc0 * inv + bb.x;
    float o1 = acc1 * inv + bb.y;
    float o2 = acc2 * inv + bb.z;
    float o3 = acc3 * inv + bb.w;
    if (do_silu) {
        o0 = o0 / (1.f + __expf(-o0));
        o1 = o1 / (1.f + __expf(-o1));
        o2 = o2 / (1.f + __expf(-o2));
        o3 = o3 / (1.f + __expf(-o3));
    }
    if (out_bf) {
        ushort us[4] = {f2bf(o0), f2bf(o1), f2bf(o2), f2bf(o3)};
        *(uint2*)(out_bf + (size_t)d * DIM + l * 4) = *(uint2*)us;
    } else {
        *(float4*)(out_f32 + (size_t)d * DIM + l * 4) = make_float4(o0, o1, o2, o3);
    }
}

// ----------- conflict detection (flags pre-zeroed by the fused memset).
__global__ __launch_bounds__(256)
void conflict_kernel(const int* __restrict__ head, const int* __restrict__ rel,
                     const int* __restrict__ g2l, const int* __restrict__ nbs,
                     int* __restrict__ flags) {
    int b = blockIdx.x;
    int rb = rel[b];
    if (rb < 4 || rb > 6) return;
    __shared__ int rd[KNB + 1];
    int t = threadIdx.x;
    if (t == 0) rd[KNB] = head[b];
    if (t < KNB) rd[t] = nbs[(size_t)g2l[head[b]] * KNB + t];
    __syncthreads();
    int rt = rel[t];
    int w = (t != b && rt >= 4 && rt <= 6) ? head[t] : -1;
    if (w >= 0) {
        bool hit = false;
#pragma unroll
        for (int k = 0; k <= KNB; ++k) hit |= (rd[k] == w);
        if (hit) { flags[b] = 1; flags[t] = 1; }
    }
}

// ----------- fused apply: blocks 0..255 = independent steps (rows untouched
// by any other step); block 256 = flagged steps in program order (each thread
// owns one column -> no barriers in the walk). Par/seq rows disjoint.
__global__ __launch_bounds__(256)
void apply_kernel(float* __restrict__ emb, const int* __restrict__ head,
                  const int* __restrict__ rel, const int* __restrict__ g2l,
                  const int* __restrict__ nbs, const float* __restrict__ wts,
                  const int* __restrict__ rhist, const int* __restrict__ flags) {
    const int t = threadIdx.x;
    if (blockIdx.x < BSZ) {
        int b = blockIdx.x;
        int r = rel[b];
        if (r < 4 || r > 6) return;
        if (flags[b]) return;
        int hi = head[b];
        int local = g2l[hi];
        int dg = rhist[(r - 4) * ND_ + local];
        float c = LAM * __expf(-LAM * (float)dg) + 0.2f;
        const int* __restrict__ nb = nbs + (size_t)local * KNB;
        const float* __restrict__ w = wts + (size_t)local * KNB;
        float v0 = 0.f, v1 = 0.f;
#pragma unroll
        for (int k = 0; k < KNB; k += 2) {
            v0 = fmaf(w[k],     emb[(size_t)nb[k] * DIM + t],     v0);
            v1 = fmaf(w[k + 1], emb[(size_t)nb[k + 1] * DIM + t], v1);
        }
        size_t idx = (size_t)hi * DIM + t;
        emb[idx] = c * (v0 + v1) + (1.f - c) * emb[idx];
        return;
    }
    // ---- sequential block ----
    __shared__ int   snb[BSZ][KNB];
    __shared__ float sw[BSZ][KNB];
    __shared__ int   sh[BSZ];
    __shared__ float sc[BSZ];
    __shared__ int   sf[BSZ];
    int r = rel[t];
    int dis = (r >= 4 && r <= 6);
    int hi = head[t];
    sh[t] = hi;
    sf[t] = dis ? flags[t] : 0;
    if (dis) {
        int local = g2l[hi];
        int dg = rhist[(r - 4) * ND_ + local];
        sc[t] = LAM * __expf(-LAM * (float)dg) + 0.2f;
#pragma unroll
        for (int k = 0; k < KNB; ++k) {
            snb[t][k] = nbs[(size_t)local * KNB + k];
            sw[t][k]  = wts[(size_t)local * KNB + k];
        }
    }
    __syncthreads();
    for (int b = 0; b < BSZ; ++b) {
        if (sf[b]) {
            int hh = sh[b];
            float c = sc[b];
            float v0 = 0.f, v1 = 0.f;
#pragma unroll
            for (int k = 0; k < KNB; k += 2) {
                v0 = fmaf(sw[b][k],     emb[(size_t)snb[b][k] * DIM + t],     v0);
                v1 = fmaf(sw[b][k + 1], emb[(size_t)snb[b][k + 1] * DIM + t], v1);
            }
            size_t idx = (size_t)hh * DIM + t;
            emb[idx] = c * (v0 + v1) + (1.f - c) * emb[idx];
        }
    }
}

// ------------------------------------------------------------------ decode
__global__ __launch_bounds__(256)
void decode_kernel(const float* __restrict__ emb, const int* __restrict__ head,
                   const int* __restrict__ rel, const int* __restrict__ tail,
                   const float* __restrict__ rel_emb, float* __restrict__ out) {
    int b = blockIdx.x, t = threadIdx.x;
    float v = emb[(size_t)head[b] * DIM + t] *
              rel_emb[(size_t)rel[b] * DIM + t] *
              emb[(size_t)tail[b] * DIM + t];
    __shared__ float red[4];
#pragma unroll
    for (int off = 32; off; off >>= 1) v += __shfl_down(v, off);
    int lane = t & 63, w = t >> 6;
    if (lane == 0) red[w] = v;
    __syncthreads();
    if (t == 0) {
        float s = red[0] + red[1] + red[2] + red[3];
        out[b] = 1.f / (1.f + expf(-s));
    }
}

// ------------------------------------------------------------------ launch
extern "C" void kernel_launch(void* const* d_in, const int* in_sizes, int n_in,
                              void* d_out, int out_size, void* d_ws, size_t ws_size,
                              hipStream_t stream) {
    const float* x        = (const float*)d_in[0];
    const int*   ei       = (const int*)d_in[1];
    const int*   head     = (const int*)d_in[2];
    const int*   rel      = (const int*)d_in[3];
    const int*   tail     = (const int*)d_in[4];
    const int*   g2l      = (const int*)d_in[5];
    const int*   res      = (const int*)d_in[6];
    const int*   nbs      = (const int*)d_in[7];
    const float* wts      = (const float*)d_in[8];
    const float* W1       = (const float*)d_in[9];
    const float* a1s      = (const float*)d_in[10];
    const float* a1d      = (const float*)d_in[11];
    const float* b1       = (const float*)d_in[12];
    const float* W2       = (const float*)d_in[13];
    const float* a2s      = (const float*)d_in[14];
    const float* a2d      = (const float*)d_in[15];
    const float* b2       = (const float*)d_in[16];
    const float* rel_emb  = (const float*)d_in[17];
    float* out = (float*)d_out;

    char* ws = (char*)d_ws;
    size_t off_b = 0;
    auto alloc = [&](size_t bytes) {
        void* pp = ws + off_b;
        off_b += (bytes + 255) & ~(size_t)255;
        return pp;
    };
    float*  bufB    = (float*)alloc((size_t)N_NODES * DIM * 4);  // layer-2 out (fp32)
    ushort* hb      = (ushort*)alloc((size_t)N_NODES * DIM * 2); // bf16 h rows (gemm out)
    ushort* h1b     = (ushort*)alloc((size_t)N_NODES * DIM * 2); // bf16 layer-1 out
    float*  hs      = (float*)alloc((size_t)N_NODES * 4);
    float*  hd      = (float*)alloc((size_t)N_NODES * 4);
    // ---- zeroed region (one fused memset) ----
    size_t z0 = off_b;
    int*    deg     = (int*)alloc((size_t)N_NODES * 4);
    int*    cnt     = (int*)alloc((size_t)N_NODES * 4);
    int*    rhist   = (int*)alloc((size_t)3 * ND_ * 4);
    int*    flags   = (int*)alloc((size_t)BSZ * 4);
    size_t z1 = off_b;
    // ------------------------------------------
    int*    offs    = (int*)alloc((size_t)(N_NODES + 1) * 4);
    int*    csr_src = (int*)alloc((size_t)N_EDGES * 4);
    int*    bsum    = (int*)alloc((size_t)NB_SCAN * 4);
    int*    bpre    = (int*)alloc((size_t)(NB_SCAN + 1) * 4);
    ushort* wpack1  = (ushort*)alloc((size_t)256 * 256 * 2);
    ushort* wpack2  = (ushort*)alloc((size_t)256 * 256 * 2);

    const int nodeBlocks4 = (N_NODES + 3) / 4;
    const int prepBlocks  = 32 + RH_BLKS + HIST_BLKS;

    // ---------------- prep: memset + {packW1|packW2|rel_hist|hist} ----------
    hipMemsetAsync(ws + z0, 0, z1 - z0, stream);   // deg + cnt + rhist + flags
    prep_kernel<<<prepBlocks, 256, 0, stream>>>(W1, W2, wpack1, wpack2,
                                                res, rhist, ei, deg);
    blockscan_kernel<<<NB_SCAN, 256, 0, stream>>>(deg, offs, bsum);
    scan_bsum_kernel<<<1, 256, 0, stream>>>(bsum, bpre);
    add_offsets_kernel<<<NB_SCAN, 256, 0, stream>>>(offs, bpre);
    scatter_kernel<<<HIST_BLKS, 256, 0, stream>>>(ei, offs, cnt, csr_src);

    // ---------------- layer 1 (A = x, fp32, staged in LDS) ----------------
    gemm_fused_kernel<1><<<GEMM_BLKS, 256, 0, stream>>>(x, nullptr, wpack1, hb,
                                                        a1s, a1d, hs, hd, N_NODES);
    gat_aggr_kernel<<<nodeBlocks4, 256, 0, stream>>>(offs, csr_src, hs, hd, hb, b1,
                                                     nullptr, h1b, 1);

    // ---------------- layer 2 (A = h1b, bf16, staged in LDS) ----------------
    gemm_fused_kernel<0><<<GEMM_BLKS, 256, 0, stream>>>(nullptr, h1b, wpack2, hb,
                                                        a2s, a2d, hs, hd, N_NODES);
    gat_aggr_kernel<<<nodeBlocks4, 256, 0, stream>>>(offs, csr_src, hs, hd, hb, b2,
                                                     bufB, nullptr, 0);

    // ---------------- scan (conflict -> fused apply) + decode ----------------
    conflict_kernel<<<BSZ, 256, 0, stream>>>(head, rel, g2l, nbs, flags);
    apply_kernel<<<BSZ + 1, 256, 0, stream>>>(bufB, head, rel, g2l, nbs, wts,
                                              rhist, flags);
    decode_kernel<<<BSZ, 256, 0, stream>>>(bufB, head, rel, tail, rel_emb, out);
}

// Round 12
// 389.524 us; speedup vs baseline: 1.1285x; 1.0087x over previous
//
#include <hip/hip_runtime.h>
#include <cstdint>

#define N_NODES 50000
#define N_EDGES 800000
#define DIM     256
#define BSZ     256
#define ND_     5000
#define KNB     16
#define ER_     20000
#define LAM     0.7f

typedef unsigned int uint;
typedef unsigned short ushort;
typedef __attribute__((ext_vector_type(8))) short bf16x8;
typedef __attribute__((ext_vector_type(4))) float f32x4;

#define NB_SCAN    ((N_NODES + 255) / 256)      // 196
#define GROWS      32                           // gemm tile rows (32: 8 blocks/CU)
#define GEMM_BLKS  ((N_NODES + GROWS - 1) / GROWS)   // 1563
#define RH_BLKS    ((3 * ER_ + 255) / 256)      // 235
#define HIST_BLKS  ((N_EDGES + 255) / 256)      // 3125

__device__ __forceinline__ ushort f2bf(float f) {
    uint u = __float_as_uint(f);
    uint r = u + 0x7FFFu + ((u >> 16) & 1u);   // round-to-nearest-even
    return (ushort)(r >> 16);
}
__device__ __forceinline__ float bflo(uint u) { return __uint_as_float(u << 16); }
__device__ __forceinline__ float bfhi(uint u) { return __uint_as_float(u & 0xffff0000u); }

// fragment k-map: elem j, lane-group lg -> kk=(j&3)+lg*4+(j>>2)*16, same
// bijection for A and B fragments (permutation cancels inside the MFMA dot).

// ---------------- pack W [K=256,N=256] f32 -> frag order (device body) ----
__device__ __forceinline__ void pack_b_body(const float* __restrict__ W,
                                            ushort* __restrict__ out, int nt, int t) {
    const int l  = t & 63;
    const int kt0 = (t >> 6) * 2;
    const int n  = nt * 16 + (l & 15);
    const int lg = l >> 4;
#pragma unroll
    for (int p = 0; p < 2; ++p) {
        int kt = kt0 + p;
        ushort us[8];
#pragma unroll
        for (int j = 0; j < 8; ++j) {
            int kk = (j & 3) + lg * 4 + (j >> 2) * 16;
            us[j] = f2bf(W[(size_t)(kt * 32 + kk) * 256 + n]);
        }
        *(uint4*)(out + ((size_t)(nt * 8 + kt) * 64 + l) * 8) = *(uint4*)us;
    }
}

// -------- merged prep: pack W1 | pack W2 | rel-hist | dst-degree hist -----
__global__ __launch_bounds__(256)
void prep_kernel(const float* __restrict__ W1, const float* __restrict__ W2,
                 ushort* __restrict__ wp1, ushort* __restrict__ wp2,
                 const int* __restrict__ res, int* __restrict__ rhist,
                 const int* __restrict__ ei, int* __restrict__ deg) {
    const int b = blockIdx.x, t = threadIdx.x;
    if (b < 16)       { pack_b_body(W1, wp1, b, t);      return; }
    if (b < 32)       { pack_b_body(W2, wp2, b - 16, t); return; }
    if (b < 32 + RH_BLKS) {
        int i = (b - 32) * 256 + t;
        if (i < 3 * ER_) atomicAdd(&rhist[(i / ER_) * ND_ + res[i]], 1);
        return;
    }
    int e = (b - 32 - RH_BLKS) * 256 + t;
    if (e < N_EDGES) atomicAdd(&deg[ei[N_EDGES + e]], 1);
}

// -------- LDS-staged bf16 MFMA GEMM + fused attention-dots epilogue -------
// H[M,256] (bf16 row-major) = A @ B ; hs/hd = H @ a_src / H @ a_dst
// A staged 32x256 per block, coalesced, XOR-swizzled chunks (c ^= row&15):
// both ds_write and fragment ds_read_b64 are bank-conflict-free.
template<int SRCF32>
__global__ __launch_bounds__(256)
void gemm_fused_kernel(const float* __restrict__ Af, const ushort* __restrict__ Ab,
                       const ushort* __restrict__ Bp, ushort* __restrict__ H,
                       const float* __restrict__ a_src, const float* __restrict__ a_dst,
                       float* __restrict__ hs, float* __restrict__ hd, int M) {
    __shared__ uint2 lda[GROWS * 64];        // chunk = 4 bf16 (8B); 16 KiB
    __shared__ float sdS[4][GROWS];
    __shared__ float sdD[4][GROWS];
    const int t = threadIdx.x;
    const int w = t >> 6;
    const int l = t & 63;
    const int rb = blockIdx.x * GROWS;

    // ---- stage A (coalesced) ----
    if (SRCF32) {
#pragma unroll
        for (int u = 0; u < 8; ++u) {
            int f = t + u * 256;              // float4 index; 64 per row
            int r = f >> 6;
            int cq = f & 63;                  // chunk (4 cols)
            int grow = rb + r;
            float4 v = (grow < M) ? *(const float4*)(Af + (size_t)grow * 256 + cq * 4)
                                  : make_float4(0.f, 0.f, 0.f, 0.f);
            uint2 o;
            o.x = (uint)f2bf(v.x) | ((uint)f2bf(v.y) << 16);
            o.y = (uint)f2bf(v.z) | ((uint)f2bf(v.w) << 16);
            lda[r * 64 + (cq ^ (r & 15))] = o;
        }
    } else {
#pragma unroll
        for (int u = 0; u < 4; ++u) {
            int f = t + u * 256;              // uint4 index; 32 per row
            int r = f >> 5;
            int p = f & 31;
            int grow = rb + r;
            uint4 v = (grow < M) ? *(const uint4*)(Ab + (size_t)grow * 256 + p * 8)
                                 : make_uint4(0u, 0u, 0u, 0u);
            int c = p * 2;
            lda[r * 64 + ( c      ^ (r & 15))] = make_uint2(v.x, v.y);
            lda[r * 64 + ((c + 1) ^ (r & 15))] = make_uint2(v.z, v.w);
        }
    }
    __syncthreads();

    // ---- MFMA ----
    const int cb = l & 15;
    const int lg = l >> 4;
    f32x4 acc[2][4];
#pragma unroll
    for (int i = 0; i < 2; ++i)
#pragma unroll
        for (int j = 0; j < 4; ++j) acc[i][j] = (f32x4){0.f, 0.f, 0.f, 0.f};

    for (int kt = 0; kt < 8; ++kt) {
        bf16x8 af[2], bfr[4];
#pragma unroll
        for (int mi = 0; mi < 2; ++mi) {
            int row = mi * 16 + cb;
            uint2 lo = lda[row * 64 + ((kt * 8 + lg)     ^ cb)];
            uint2 hi = lda[row * 64 + ((kt * 8 + lg + 4) ^ cb)];
            uint4 cmb; cmb.x = lo.x; cmb.y = lo.y; cmb.z = hi.x; cmb.w = hi.y;
            af[mi] = *(bf16x8*)&cmb;
        }
#pragma unroll
        for (int ni = 0; ni < 4; ++ni)
            bfr[ni] = *(const bf16x8*)(Bp + ((size_t)((w * 4 + ni) * 8 + kt) * 64 + l) * 8);
#pragma unroll
        for (int mi = 0; mi < 2; ++mi)
#pragma unroll
            for (int ni = 0; ni < 4; ++ni)
                acc[mi][ni] = __builtin_amdgcn_mfma_f32_16x16x32_bf16(
                    af[mi], bfr[ni], acc[mi][ni], 0, 0, 0);
    }

    // ---- epilogue: H store + fused dots (C/D: col=lane&15, row=(lane>>4)*4+reg) ----
    const int rbase = (l >> 4) * 4;
    float asv[4], adv[4];
#pragma unroll
    for (int ni = 0; ni < 4; ++ni) {
        int col = (w * 4 + ni) * 16 + cb;
        asv[ni] = a_src[col];
        adv[ni] = a_dst[col];
    }
#pragma unroll
    for (int mi = 0; mi < 2; ++mi) {
#pragma unroll
        for (int r = 0; r < 4; ++r) {
            int row = rb + mi * 16 + rbase + r;
            float ps = 0.f, pd = 0.f;
#pragma unroll
            for (int ni = 0; ni < 4; ++ni) {
                float hv = acc[mi][ni][r];
                ps = fmaf(hv, asv[ni], ps);
                pd = fmaf(hv, adv[ni], pd);
                if (row < M) {
                    int col = (w * 4 + ni) * 16 + cb;
                    H[(size_t)row * 256 + col] = f2bf(hv);
                }
            }
#pragma unroll
            for (int o = 1; o < 16; o <<= 1) {
                ps += __shfl_xor(ps, o);
                pd += __shfl_xor(pd, o);
            }
            if (cb == 0) {
                sdS[w][mi * 16 + rbase + r] = ps;
                sdD[w][mi * 16 + rbase + r] = pd;
            }
        }
    }
    __syncthreads();
    if (t < GROWS) {
        int row = rb + t;
        if (row < M) {
            hs[row] = sdS[0][t] + sdS[1][t] + sdS[2][t] + sdS[3][t];
            hd[row] = sdD[0][t] + sdD[1][t] + sdD[2][t] + sdD[3][t];
        }
    }
}

// -------- two-level parallel exclusive scan of deg -> offs --------
__global__ __launch_bounds__(256)
void blockscan_kernel(const int* __restrict__ deg, int* __restrict__ off,
                      int* __restrict__ bsum) {
    __shared__ int s[256];
    const int b = blockIdx.x, t = threadIdx.x;
    const int idx = b * 256 + t;
    int v = (idx < N_NODES) ? deg[idx] : 0;
    s[t] = v;
    __syncthreads();
    for (int o = 1; o < 256; o <<= 1) {
        int x = (t >= o) ? s[t - o] : 0;
        __syncthreads();
        s[t] += x;
        __syncthreads();
    }
    if (idx < N_NODES) off[idx] = s[t] - v;
    if (t == 255) bsum[b] = s[255];
}

__global__ __launch_bounds__(256)
void scan_bsum_kernel(const int* __restrict__ bsum, int* __restrict__ bpre) {
    __shared__ int s[256];
    const int t = threadIdx.x;
    int v = (t < NB_SCAN) ? bsum[t] : 0;
    s[t] = v;
    __syncthreads();
    for (int o = 1; o < 256; o <<= 1) {
        int x = (t >= o) ? s[t - o] : 0;
        __syncthreads();
        s[t] += x;
        __syncthreads();
    }
    if (t < NB_SCAN) bpre[t] = s[t] - v;
    if (t == 255) bpre[NB_SCAN] = s[255];
}

__global__ __launch_bounds__(256)
void add_offsets_kernel(int* __restrict__ off, const int* __restrict__ bpre) {
    const int b = blockIdx.x, t = threadIdx.x;
    const int idx = b * 256 + t;
    if (idx < N_NODES) off[idx] += bpre[b];
    if (b == NB_SCAN - 1 && t == 255) off[N_NODES] = bpre[NB_SCAN];
}

// cnt-based scatter (offs left intact -> rocprof replay-safe)
__global__ __launch_bounds__(256)
void scatter_kernel(const int* __restrict__ ei, const int* __restrict__ off,
                    int* __restrict__ cnt, int* __restrict__ csr_src) {
    int e = blockIdx.x * 256 + threadIdx.x;
    if (e >= N_EDGES) return;
    int d = ei[N_EDGES + e];
    int pos = atomicAdd(&cnt[d], 1);
    csr_src[off[d] + pos] = ei[e];
}

// ----------------- fused GAT edge stage: wave-per-dst, no max, no barriers
// 8x-unrolled gather: 8 independent row loads in flight per latency wait.
__global__ __launch_bounds__(256)
void gat_aggr_kernel(const int* __restrict__ off, const int* __restrict__ csr_src,
                     const float* __restrict__ hs, const float* __restrict__ hd,
                     const ushort* __restrict__ hb, const float* __restrict__ bias,
                     float* __restrict__ out_f32, ushort* __restrict__ out_bf,
                     int do_silu) {
    const int d = blockIdx.x * 4 + (threadIdx.x >> 6);
    const int l = threadIdx.x & 63;
    if (d >= N_NODES) return;
    const int beg = off[d], end = off[d + 1];
    const float hdd = hd[d];

    float acc0 = 0.f, acc1 = 0.f, acc2 = 0.f, acc3 = 0.f;
    float zl = 0.f;
    const ushort* __restrict__ hcol = hb + l * 4;

    for (int c0 = beg; c0 < end; c0 += 64) {
        const int cn = min(end - c0, 64);
        int s = 0; float pexp = 0.f;
        if (l < cn) {
            s = csr_src[c0 + l];
            float v = hs[s] + hdd;
            v = (v >= 0.f) ? v : 0.2f * v;
            pexp = __expf(v);
        }
        zl += pexp;
        int j = 0;
        for (; j + 8 <= cn; j += 8) {
            int   s0 = __shfl(s, j),     s1 = __shfl(s, j + 1);
            int   s2 = __shfl(s, j + 2), s3 = __shfl(s, j + 3);
            int   s4 = __shfl(s, j + 4), s5 = __shfl(s, j + 5);
            int   s6 = __shfl(s, j + 6), s7 = __shfl(s, j + 7);
            float p0 = __shfl(pexp, j),     p1 = __shfl(pexp, j + 1);
            float p2 = __shfl(pexp, j + 2), p3 = __shfl(pexp, j + 3);
            float p4 = __shfl(pexp, j + 4), p5 = __shfl(pexp, j + 5);
            float p6 = __shfl(pexp, j + 6), p7 = __shfl(pexp, j + 7);
            uint2 r0 = *(const uint2*)(hcol + (size_t)s0 * DIM);
            uint2 r1 = *(const uint2*)(hcol + (size_t)s1 * DIM);
            uint2 r2 = *(const uint2*)(hcol + (size_t)s2 * DIM);
            uint2 r3 = *(const uint2*)(hcol + (size_t)s3 * DIM);
            uint2 r4 = *(const uint2*)(hcol + (size_t)s4 * DIM);
            uint2 r5 = *(const uint2*)(hcol + (size_t)s5 * DIM);
            uint2 r6 = *(const uint2*)(hcol + (size_t)s6 * DIM);
            uint2 r7 = *(const uint2*)(hcol + (size_t)s7 * DIM);
            acc0 = fmaf(p0, bflo(r0.x), acc0); acc1 = fmaf(p0, bfhi(r0.x), acc1);
            acc2 = fmaf(p0, bflo(r0.y), acc2); acc3 = fmaf(p0, bfhi(r0.y), acc3);
            acc0 = fmaf(p1, bflo(r1.x), acc0); acc1 = fmaf(p1, bfhi(r1.x), acc1);
            acc2 = fmaf(p1, bflo(r1.y), acc2); acc3 = fmaf(p1, bfhi(r1.y), acc3);
            acc0 = fmaf(p2, bflo(r2.x), acc0); acc1 = fmaf(p2, bfhi(r2.x), acc1);
            acc2 = fmaf(p2, bflo(r2.y), acc2); acc3 = fmaf(p2, bfhi(r2.y), acc3);
            acc0 = fmaf(p3, bflo(r3.x), acc0); acc1 = fmaf(p3, bfhi(r3.x), acc1);
            acc2 = fmaf(p3, bflo(r3.y), acc2); acc3 = fmaf(p3, bfhi(r3.y), acc3);
            acc0 = fmaf(p4, bflo(r4.x), acc0); acc1 = fmaf(p4, bfhi(r4.x), acc1);
            acc2 = fmaf(p4, bflo(r4.y), acc2); acc3 = fmaf(p4, bfhi(r4.y), acc3);
            acc0 = fmaf(p5, bflo(r5.x), acc0); acc1 = fmaf(p5, bfhi(r5.x), acc1);
            acc2 = fmaf(p5, bflo(r5.y), acc2); acc3 = fmaf(p5, bfhi(r5.y), acc3);
            acc0 = fmaf(p6, bflo(r6.x), acc0); acc1 = fmaf(p6, bfhi(r6.x), acc1);
            acc2 = fmaf(p6, bflo(r6.y), acc2); acc3 = fmaf(p6, bfhi(r6.y), acc3);
            acc0 = fmaf(p7, bflo(r7.x), acc0); acc1 = fmaf(p7, bfhi(r7.x), acc1);
            acc2 = fmaf(p7, bflo(r7.y), acc2); acc3 = fmaf(p7, bfhi(r7.y), acc3);
        }
        for (; j + 4 <= cn; j += 4) {
            int   s0 = __shfl(s, j),     s1 = __shfl(s, j + 1);
            int   s2 = __shfl(s, j + 2), s3 = __shfl(s, j + 3);
            float p0 = __shfl(pexp, j),     p1 = __shfl(pexp, j + 1);
            float p2 = __shfl(pexp, j + 2), p3 = __shfl(pexp, j + 3);
            uint2 r0 = *(const uint2*)(hcol + (size_t)s0 * DIM);
            uint2 r1 = *(const uint2*)(hcol + (size_t)s1 * DIM);
            uint2 r2 = *(const uint2*)(hcol + (size_t)s2 * DIM);
            uint2 r3 = *(const uint2*)(hcol + (size_t)s3 * DIM);
            acc0 = fmaf(p0, bflo(r0.x), acc0); acc1 = fmaf(p0, bfhi(r0.x), acc1);
            acc2 = fmaf(p0, bflo(r0.y), acc2); acc3 = fmaf(p0, bfhi(r0.y), acc3);
            acc0 = fmaf(p1, bflo(r1.x), acc0); acc1 = fmaf(p1, bfhi(r1.x), acc1);
            acc2 = fmaf(p1, bflo(r1.y), acc2); acc3 = fmaf(p1, bfhi(r1.y), acc3);
            acc0 = fmaf(p2, bflo(r2.x), acc0); acc1 = fmaf(p2, bfhi(r2.x), acc1);
            acc2 = fmaf(p2, bflo(r2.y), acc2); acc3 = fmaf(p2, bfhi(r2.y), acc3);
            acc0 = fmaf(p3, bflo(r3.x), acc0); acc1 = fmaf(p3, bfhi(r3.x), acc1);
            acc2 = fmaf(p3, bflo(r3.y), acc2); acc3 = fmaf(p3, bfhi(r3.y), acc3);
        }
        for (; j < cn; ++j) {
            int   sj = __shfl(s, j);
            float pj = __shfl(pexp, j);
            uint2 rv = *(const uint2*)(hcol + (size_t)sj * DIM);
            acc0 = fmaf(pj, bflo(rv.x), acc0); acc1 = fmaf(pj, bfhi(rv.x), acc1);
            acc2 = fmaf(pj, bflo(rv.y), acc2); acc3 = fmaf(pj, bfhi(rv.y), acc3);
        }
    }
    float z = zl;
#pragma unroll
    for (int o = 32; o; o >>= 1) z += __shfl_xor(z, o);
    const float inv = (end > beg) ? 1.f / (z + 1e-16f) : 0.f;
    float4 bb = *(const float4*)(bias + l * 4);
    float o0 = acc0 * inv + bb.x;
    float o1 = acc1 * inv + bb.y;
    float o2 = acc2 * inv + bb.z;
    float o3 = acc3 * inv + bb.w;
    if (do_silu) {
        o0 = o0 / (1.f + __expf(-o0));
        o1 = o1 / (1.f + __expf(-o1));
        o2 = o2 / (1.f + __expf(-o2));
        o3 = o3 / (1.f + __expf(-o3));
    }
    if (out_bf) {
        ushort us[4] = {f2bf(o0), f2bf(o1), f2bf(o2), f2bf(o3)};
        *(uint2*)(out_bf + (size_t)d * DIM + l * 4) = *(uint2*)us;
    } else {
        *(float4*)(out_f32 + (size_t)d * DIM + l * 4) = make_float4(o0, o1, o2, o3);
    }
}

// ----------- conflict detection (flags pre-zeroed by the fused memset).
__global__ __launch_bounds__(256)
void conflict_kernel(const int* __restrict__ head, const int* __restrict__ rel,
                     const int* __restrict__ g2l, const int* __restrict__ nbs,
                     int* __restrict__ flags) {
    int b = blockIdx.x;
    int rb = rel[b];
    if (rb < 4 || rb > 6) return;
    __shared__ int rd[KNB + 1];
    int t = threadIdx.x;
    if (t == 0) rd[KNB] = head[b];
    if (t < KNB) rd[t] = nbs[(size_t)g2l[head[b]] * KNB + t];
    __syncthreads();
    int rt = rel[t];
    int w = (t != b && rt >= 4 && rt <= 6) ? head[t] : -1;
    if (w >= 0) {
        bool hit = false;
#pragma unroll
        for (int k = 0; k <= KNB; ++k) hit |= (rd[k] == w);
        if (hit) { flags[b] = 1; flags[t] = 1; }
    }
}

// ----------- fused apply: blocks 0..255 = independent steps (rows untouched
// by any other step); block 256 = flagged steps in program order (each thread
// owns one column -> no barriers in the walk). Par/seq rows disjoint.
__global__ __launch_bounds__(256)
void apply_kernel(float* __restrict__ emb, const int* __restrict__ head,
                  const int* __restrict__ rel, const int* __restrict__ g2l,
                  const int* __restrict__ nbs, const float* __restrict__ wts,
                  const int* __restrict__ rhist, const int* __restrict__ flags) {
    const int t = threadIdx.x;
    if (blockIdx.x < BSZ) {
        int b = blockIdx.x;
        int r = rel[b];
        if (r < 4 || r > 6) return;
        if (flags[b]) return;
        int hi = head[b];
        int local = g2l[hi];
        int dg = rhist[(r - 4) * ND_ + local];
        float c = LAM * __expf(-LAM * (float)dg) + 0.2f;
        const int* __restrict__ nb = nbs + (size_t)local * KNB;
        const float* __restrict__ w = wts + (size_t)local * KNB;
        float v0 = 0.f, v1 = 0.f;
#pragma unroll
        for (int k = 0; k < KNB; k += 2) {
            v0 = fmaf(w[k],     emb[(size_t)nb[k] * DIM + t],     v0);
            v1 = fmaf(w[k + 1], emb[(size_t)nb[k + 1] * DIM + t], v1);
        }
        size_t idx = (size_t)hi * DIM + t;
        emb[idx] = c * (v0 + v1) + (1.f - c) * emb[idx];
        return;
    }
    // ---- sequential block ----
    __shared__ int   snb[BSZ][KNB];
    __shared__ float sw[BSZ][KNB];
    __shared__ int   sh[BSZ];
    __shared__ float sc[BSZ];
    __shared__ int   sf[BSZ];
    int r = rel[t];
    int dis = (r >= 4 && r <= 6);
    int hi = head[t];
    sh[t] = hi;
    sf[t] = dis ? flags[t] : 0;
    if (dis) {
        int local = g2l[hi];
        int dg = rhist[(r - 4) * ND_ + local];
        sc[t] = LAM * __expf(-LAM * (float)dg) + 0.2f;
#pragma unroll
        for (int k = 0; k < KNB; ++k) {
            snb[t][k] = nbs[(size_t)local * KNB + k];
            sw[t][k]  = wts[(size_t)local * KNB + k];
        }
    }
    __syncthreads();
    for (int b = 0; b < BSZ; ++b) {
        if (sf[b]) {
            int hh = sh[b];
            float c = sc[b];
            float v0 = 0.f, v1 = 0.f;
#pragma unroll
            for (int k = 0; k < KNB; k += 2) {
                v0 = fmaf(sw[b][k],     emb[(size_t)snb[b][k] * DIM + t],     v0);
                v1 = fmaf(sw[b][k + 1], emb[(size_t)snb[b][k + 1] * DIM + t], v1);
            }
            size_t idx = (size_t)hh * DIM + t;
            emb[idx] = c * (v0 + v1) + (1.f - c) * emb[idx];
        }
    }
}

// ------------------------------------------------------------------ decode
__global__ __launch_bounds__(256)
void decode_kernel(const float* __restrict__ emb, const int* __restrict__ head,
                   const int* __restrict__ rel, const int* __restrict__ tail,
                   const float* __restrict__ rel_emb, float* __restrict__ out) {
    int b = blockIdx.x, t = threadIdx.x;
    float v = emb[(size_t)head[b] * DIM + t] *
              rel_emb[(size_t)rel[b] * DIM + t] *
              emb[(size_t)tail[b] * DIM + t];
    __shared__ float red[4];
#pragma unroll
    for (int off = 32; off; off >>= 1) v += __shfl_down(v, off);
    int lane = t & 63, w = t >> 6;
    if (lane == 0) red[w] = v;
    __syncthreads();
    if (t == 0) {
        float s = red[0] + red[1] + red[2] + red[3];
        out[b] = 1.f / (1.f + expf(-s));
    }
}

// ------------------------------------------------------------------ launch
extern "C" void kernel_launch(void* const* d_in, const int* in_sizes, int n_in,
                              void* d_out, int out_size, void* d_ws, size_t ws_size,
                              hipStream_t stream) {
    const float* x        = (const float*)d_in[0];
    const int*   ei       = (const int*)d_in[1];
    const int*   head     = (const int*)d_in[2];
    const int*   rel      = (const int*)d_in[3];
    const int*   tail     = (const int*)d_in[4];
    const int*   g2l      = (const int*)d_in[5];
    const int*   res      = (const int*)d_in[6];
    const int*   nbs      = (const int*)d_in[7];
    const float* wts      = (const float*)d_in[8];
    const float* W1       = (const float*)d_in[9];
    const float* a1s      = (const float*)d_in[10];
    const float* a1d      = (const float*)d_in[11];
    const float* b1       = (const float*)d_in[12];
    const float* W2       = (const float*)d_in[13];
    const float* a2s      = (const float*)d_in[14];
    const float* a2d      = (const float*)d_in[15];
    const float* b2       = (const float*)d_in[16];
    const float* rel_emb  = (const float*)d_in[17];
    float* out = (float*)d_out;

    char* ws = (char*)d_ws;
    size_t off_b = 0;
    auto alloc = [&](size_t bytes) {
        void* pp = ws + off_b;
        off_b += (bytes + 255) & ~(size_t)255;
        return pp;
    };
    float*  bufB    = (float*)alloc((size_t)N_NODES * DIM * 4);  // layer-2 out (fp32)
    ushort* hb      = (ushort*)alloc((size_t)N_NODES * DIM * 2); // bf16 h rows (gemm out)
    ushort* h1b     = (ushort*)alloc((size_t)N_NODES * DIM * 2); // bf16 layer-1 out
    float*  hs      = (float*)alloc((size_t)N_NODES * 4);
    float*  hd      = (float*)alloc((size_t)N_NODES * 4);
    // ---- zeroed region (one fused memset) ----
    size_t z0 = off_b;
    int*    deg     = (int*)alloc((size_t)N_NODES * 4);
    int*    cnt     = (int*)alloc((size_t)N_NODES * 4);
    int*    rhist   = (int*)alloc((size_t)3 * ND_ * 4);
    int*    flags   = (int*)alloc((size_t)BSZ * 4);
    size_t z1 = off_b;
    // ------------------------------------------
    int*    offs    = (int*)alloc((size_t)(N_NODES + 1) * 4);
    int*    csr_src = (int*)alloc((size_t)N_EDGES * 4);
    int*    bsum    = (int*)alloc((size_t)NB_SCAN * 4);
    int*    bpre    = (int*)alloc((size_t)(NB_SCAN + 1) * 4);
    ushort* wpack1  = (ushort*)alloc((size_t)256 * 256 * 2);
    ushort* wpack2  = (ushort*)alloc((size_t)256 * 256 * 2);

    const int nodeBlocks4 = (N_NODES + 3) / 4;
    const int prepBlocks  = 32 + RH_BLKS + HIST_BLKS;

    // ---------------- prep: memset + {packW1|packW2|rel_hist|hist} ----------
    hipMemsetAsync(ws + z0, 0, z1 - z0, stream);   // deg + cnt + rhist + flags
    prep_kernel<<<prepBlocks, 256, 0, stream>>>(W1, W2, wpack1, wpack2,
                                                res, rhist, ei, deg);
    blockscan_kernel<<<NB_SCAN, 256, 0, stream>>>(deg, offs, bsum);
    scan_bsum_kernel<<<1, 256, 0, stream>>>(bsum, bpre);
    add_offsets_kernel<<<NB_SCAN, 256, 0, stream>>>(offs, bpre);
    scatter_kernel<<<HIST_BLKS, 256, 0, stream>>>(ei, offs, cnt, csr_src);

    // ---------------- layer 1 (A = x, fp32, staged in LDS) ----------------
    gemm_fused_kernel<1><<<GEMM_BLKS, 256, 0, stream>>>(x, nullptr, wpack1, hb,
                                                        a1s, a1d, hs, hd, N_NODES);
    gat_aggr_kernel<<<nodeBlocks4, 256, 0, stream>>>(offs, csr_src, hs, hd, hb, b1,
                                                     nullptr, h1b, 1);

    // ---------------- layer 2 (A = h1b, bf16, staged in LDS) ----------------
    gemm_fused_kernel<0><<<GEMM_BLKS, 256, 0, stream>>>(nullptr, h1b, wpack2, hb,
                                                        a2s, a2d, hs, hd, N_NODES);
    gat_aggr_kernel<<<nodeBlocks4, 256, 0, stream>>>(offs, csr_src, hs, hd, hb, b2,
                                                     bufB, nullptr, 0);

    // ---------------- scan (conflict -> fused apply) + decode ----------------
    conflict_kernel<<<BSZ, 256, 0, stream>>>(head, rel, g2l, nbs, flags);
    apply_kernel<<<BSZ + 1, 256, 0, stream>>>(bufB, head, rel, g2l, nbs, wts,
                                              rhist, flags);
    decode_kernel<<<BSZ, 256, 0, stream>>>(bufB, head, rel, tail, rel_emb, out);
}

// Round 13
// 385.263 us; speedup vs baseline: 1.1410x; 1.0111x over previous
//
#include <hip/hip_runtime.h>
#include <cstdint>

#define N_NODES 50000
#define N_EDGES 800000
#define DIM     256
#define BSZ     256
#define ND_     5000
#define KNB     16
#define ER_     20000
#define LAM     0.7f

typedef unsigned int uint;
typedef unsigned short ushort;
typedef __attribute__((ext_vector_type(8))) short bf16x8;
typedef __attribute__((ext_vector_type(4))) float f32x4;

#define NB_SCAN    ((N_NODES + 255) / 256)      // 196
#define GROWS      32                           // gemm tile rows
#define GEMM_BLKS  ((N_NODES + GROWS - 1) / GROWS)   // 1563
#define RH_BLKS    ((3 * ER_ + 255) / 256)      // 235
#define HIST_BLKS  ((N_EDGES + 255) / 256)      // 3125

__device__ __forceinline__ ushort f2bf(float f) {
    uint u = __float_as_uint(f);
    uint r = u + 0x7FFFu + ((u >> 16) & 1u);   // round-to-nearest-even
    return (ushort)(r >> 16);
}
__device__ __forceinline__ float bflo(uint u) { return __uint_as_float(u << 16); }
__device__ __forceinline__ float bfhi(uint u) { return __uint_as_float(u & 0xffff0000u); }

// fragment k-map: elem j, lane-group lg -> kk=(j&3)+lg*4+(j>>2)*16, same
// bijection for A and B fragments (permutation cancels inside the MFMA dot).

// ---------------- pack W [K=256,N=256] f32 -> frag order (device body) ----
__device__ __forceinline__ void pack_b_body(const float* __restrict__ W,
                                            ushort* __restrict__ out, int nt, int t) {
    const int l  = t & 63;
    const int kt0 = (t >> 6) * 2;
    const int n  = nt * 16 + (l & 15);
    const int lg = l >> 4;
#pragma unroll
    for (int p = 0; p < 2; ++p) {
        int kt = kt0 + p;
        ushort us[8];
#pragma unroll
        for (int j = 0; j < 8; ++j) {
            int kk = (j & 3) + lg * 4 + (j >> 2) * 16;
            us[j] = f2bf(W[(size_t)(kt * 32 + kk) * 256 + n]);
        }
        *(uint4*)(out + ((size_t)(nt * 8 + kt) * 64 + l) * 8) = *(uint4*)us;
    }
}

// -------- merged prep: pack W1 | pack W2 | rel-hist | dst-degree hist -----
__global__ __launch_bounds__(256)
void prep_kernel(const float* __restrict__ W1, const float* __restrict__ W2,
                 ushort* __restrict__ wp1, ushort* __restrict__ wp2,
                 const int* __restrict__ res, int* __restrict__ rhist,
                 const int* __restrict__ ei, int* __restrict__ deg) {
    const int b = blockIdx.x, t = threadIdx.x;
    if (b < 16)       { pack_b_body(W1, wp1, b, t);      return; }
    if (b < 32)       { pack_b_body(W2, wp2, b - 16, t); return; }
    if (b < 32 + RH_BLKS) {
        int i = (b - 32) * 256 + t;
        if (i < 3 * ER_) atomicAdd(&rhist[(i / ER_) * ND_ + res[i]], 1);
        return;
    }
    int e = (b - 32 - RH_BLKS) * 256 + t;
    if (e < N_EDGES) atomicAdd(&deg[ei[N_EDGES + e]], 1);
}

// -------- LDS-staged bf16 MFMA GEMM + LDS-transpose epilogue --------------
// H[M,256] (bf16 row-major) = A @ B ; hs/hd = H @ a_src / H @ a_dst.
// A staged 32x256 per block (XOR-swizzled chunks, conflict-free both ways).
// Epilogue: acc fragments -> LDS bf16 tile (chunk-swizzled) -> coalesced
// uint4 global stores + fused hs/hd dots (half-wave shfl reduce). This
// replaces 32 scalar ushort global stores per lane (the R11/R12 wall).
template<int SRCF32>
__global__ __launch_bounds__(256)
void gemm_fused_kernel(const float* __restrict__ Af, const ushort* __restrict__ Ab,
                       const ushort* __restrict__ Bp, ushort* __restrict__ H,
                       const float* __restrict__ a_src, const float* __restrict__ a_dst,
                       float* __restrict__ hs, float* __restrict__ hd, int M) {
    __shared__ uint2 lda[GROWS * 64];        // 16 KiB; reused as H-tile in epilogue
    const int t = threadIdx.x;
    const int w = t >> 6;
    const int l = t & 63;
    const int rb = blockIdx.x * GROWS;

    // ---- stage A (coalesced) ----
    if (SRCF32) {
#pragma unroll
        for (int u = 0; u < 8; ++u) {
            int f = t + u * 256;              // float4 index; 64 per row
            int r = f >> 6;
            int cq = f & 63;                  // chunk (4 cols)
            int grow = rb + r;
            float4 v = (grow < M) ? *(const float4*)(Af + (size_t)grow * 256 + cq * 4)
                                  : make_float4(0.f, 0.f, 0.f, 0.f);
            uint2 o;
            o.x = (uint)f2bf(v.x) | ((uint)f2bf(v.y) << 16);
            o.y = (uint)f2bf(v.z) | ((uint)f2bf(v.w) << 16);
            lda[r * 64 + (cq ^ (r & 15))] = o;
        }
    } else {
#pragma unroll
        for (int u = 0; u < 4; ++u) {
            int f = t + u * 256;              // uint4 index; 32 per row
            int r = f >> 5;
            int p = f & 31;
            int grow = rb + r;
            uint4 v = (grow < M) ? *(const uint4*)(Ab + (size_t)grow * 256 + p * 8)
                                 : make_uint4(0u, 0u, 0u, 0u);
            int c = p * 2;
            lda[r * 64 + ( c      ^ (r & 15))] = make_uint2(v.x, v.y);
            lda[r * 64 + ((c + 1) ^ (r & 15))] = make_uint2(v.z, v.w);
        }
    }
    __syncthreads();

    // ---- MFMA ----
    const int cb = l & 15;
    const int lg = l >> 4;
    f32x4 acc[2][4];
#pragma unroll
    for (int i = 0; i < 2; ++i)
#pragma unroll
        for (int j = 0; j < 4; ++j) acc[i][j] = (f32x4){0.f, 0.f, 0.f, 0.f};

    for (int kt = 0; kt < 8; ++kt) {
        bf16x8 af[2], bfr[4];
#pragma unroll
        for (int mi = 0; mi < 2; ++mi) {
            int row = mi * 16 + cb;
            uint2 lo = lda[row * 64 + ((kt * 8 + lg)     ^ cb)];
            uint2 hi = lda[row * 64 + ((kt * 8 + lg + 4) ^ cb)];
            uint4 cmb; cmb.x = lo.x; cmb.y = lo.y; cmb.z = hi.x; cmb.w = hi.y;
            af[mi] = *(bf16x8*)&cmb;
        }
#pragma unroll
        for (int ni = 0; ni < 4; ++ni)
            bfr[ni] = *(const bf16x8*)(Bp + ((size_t)((w * 4 + ni) * 8 + kt) * 64 + l) * 8);
#pragma unroll
        for (int mi = 0; mi < 2; ++mi)
#pragma unroll
            for (int ni = 0; ni < 4; ++ni)
                acc[mi][ni] = __builtin_amdgcn_mfma_f32_16x16x32_bf16(
                    af[mi], bfr[ni], acc[mi][ni], 0, 0, 0);
    }

    // ---- epilogue: acc -> LDS bf16 tile (chunk-swizzled), then coalesced out
    __syncthreads();                          // all lda reads done; reuse buffer
    ushort* h_lds = (ushort*)lda;             // [32][256] bf16 = 16 KiB
    const int rbase = (l >> 4) * 4;           // C/D: col=lane&15, row=(lane>>4)*4+reg
#pragma unroll
    for (int mi = 0; mi < 2; ++mi) {
#pragma unroll
        for (int r = 0; r < 4; ++r) {
            int row = mi * 16 + rbase + r;
            int sw  = ((row >> 2) & 3) << 1;  // chunk XOR: spreads 4 row-groups
#pragma unroll
            for (int ni = 0; ni < 4; ++ni) {
                int col = (w * 4 + ni) * 16 + cb;
                int ch  = (col >> 3) ^ sw;
                h_lds[row * 256 + ch * 8 + (col & 7)] = f2bf(acc[mi][ni][r]);
            }
        }
    }
    __syncthreads();
    // write-out + fused dots: per iter, 32 consecutive half-wave lanes own one row
#pragma unroll
    for (int it = 0; it < 4; ++it) {
        int row = it * 8 + (t >> 5);          // 0..31
        int chl = t & 31;                     // logical chunk (8 elems)
        int sw  = ((row >> 2) & 3) << 1;
        uint4 v = *(const uint4*)(h_lds + row * 256 + (chl ^ sw) * 8);
        int c0  = chl * 8;
        float4 as0 = *(const float4*)(a_src + c0);
        float4 as1 = *(const float4*)(a_src + c0 + 4);
        float4 ad0 = *(const float4*)(a_dst + c0);
        float4 ad1 = *(const float4*)(a_dst + c0 + 4);
        float e0 = bflo(v.x), e1 = bfhi(v.x), e2 = bflo(v.y), e3 = bfhi(v.y);
        float e4 = bflo(v.z), e5 = bfhi(v.z), e6 = bflo(v.w), e7 = bfhi(v.w);
        float ps = e0 * as0.x + e1 * as0.y + e2 * as0.z + e3 * as0.w
                 + e4 * as1.x + e5 * as1.y + e6 * as1.z + e7 * as1.w;
        float pd = e0 * ad0.x + e1 * ad0.y + e2 * ad0.z + e3 * ad0.w
                 + e4 * ad1.x + e5 * ad1.y + e6 * ad1.z + e7 * ad1.w;
#pragma unroll
        for (int o = 16; o; o >>= 1) {
            ps += __shfl_down(ps, o, 32);
            pd += __shfl_down(pd, o, 32);
        }
        int grow = rb + row;
        if (grow < M) {
            *(uint4*)(H + (size_t)grow * 256 + c0) = v;
            if (chl == 0) { hs[grow] = ps; hd[grow] = pd; }
        }
    }
}

// -------- two-level parallel exclusive scan of deg -> offs --------
__global__ __launch_bounds__(256)
void blockscan_kernel(const int* __restrict__ deg, int* __restrict__ off,
                      int* __restrict__ bsum) {
    __shared__ int s[256];
    const int b = blockIdx.x, t = threadIdx.x;
    const int idx = b * 256 + t;
    int v = (idx < N_NODES) ? deg[idx] : 0;
    s[t] = v;
    __syncthreads();
    for (int o = 1; o < 256; o <<= 1) {
        int x = (t >= o) ? s[t - o] : 0;
        __syncthreads();
        s[t] += x;
        __syncthreads();
    }
    if (idx < N_NODES) off[idx] = s[t] - v;
    if (t == 255) bsum[b] = s[255];
}

__global__ __launch_bounds__(256)
void scan_bsum_kernel(const int* __restrict__ bsum, int* __restrict__ bpre) {
    __shared__ int s[256];
    const int t = threadIdx.x;
    int v = (t < NB_SCAN) ? bsum[t] : 0;
    s[t] = v;
    __syncthreads();
    for (int o = 1; o < 256; o <<= 1) {
        int x = (t >= o) ? s[t - o] : 0;
        __syncthreads();
        s[t] += x;
        __syncthreads();
    }
    if (t < NB_SCAN) bpre[t] = s[t] - v;
    if (t == 255) bpre[NB_SCAN] = s[255];
}

__global__ __launch_bounds__(256)
void add_offsets_kernel(int* __restrict__ off, const int* __restrict__ bpre) {
    const int b = blockIdx.x, t = threadIdx.x;
    const int idx = b * 256 + t;
    if (idx < N_NODES) off[idx] += bpre[b];
    if (b == NB_SCAN - 1 && t == 255) off[N_NODES] = bpre[NB_SCAN];
}

// cnt-based scatter (offs left intact -> rocprof replay-safe)
__global__ __launch_bounds__(256)
void scatter_kernel(const int* __restrict__ ei, const int* __restrict__ off,
                    int* __restrict__ cnt, int* __restrict__ csr_src) {
    int e = blockIdx.x * 256 + threadIdx.x;
    if (e >= N_EDGES) return;
    int d = ei[N_EDGES + e];
    int pos = atomicAdd(&cnt[d], 1);
    csr_src[off[d] + pos] = ei[e];
}

// ----------------- fused GAT edge stage: wave-per-dst, no max, no barriers
// 8x-unrolled gather: 8 independent row loads in flight per latency wait.
__global__ __launch_bounds__(256)
void gat_aggr_kernel(const int* __restrict__ off, const int* __restrict__ csr_src,
                     const float* __restrict__ hs, const float* __restrict__ hd,
                     const ushort* __restrict__ hb, const float* __restrict__ bias,
                     float* __restrict__ out_f32, ushort* __restrict__ out_bf,
                     int do_silu) {
    const int d = blockIdx.x * 4 + (threadIdx.x >> 6);
    const int l = threadIdx.x & 63;
    if (d >= N_NODES) return;
    const int beg = off[d], end = off[d + 1];
    const float hdd = hd[d];

    float acc0 = 0.f, acc1 = 0.f, acc2 = 0.f, acc3 = 0.f;
    float zl = 0.f;
    const ushort* __restrict__ hcol = hb + l * 4;

    for (int c0 = beg; c0 < end; c0 += 64) {
        const int cn = min(end - c0, 64);
        int s = 0; float pexp = 0.f;
        if (l < cn) {
            s = csr_src[c0 + l];
            float v = hs[s] + hdd;
            v = (v >= 0.f) ? v : 0.2f * v;
            pexp = __expf(v);
        }
        zl += pexp;
        int j = 0;
        for (; j + 8 <= cn; j += 8) {
            int   s0 = __shfl(s, j),     s1 = __shfl(s, j + 1);
            int   s2 = __shfl(s, j + 2), s3 = __shfl(s, j + 3);
            int   s4 = __shfl(s, j + 4), s5 = __shfl(s, j + 5);
            int   s6 = __shfl(s, j + 6), s7 = __shfl(s, j + 7);
            float p0 = __shfl(pexp, j),     p1 = __shfl(pexp, j + 1);
            float p2 = __shfl(pexp, j + 2), p3 = __shfl(pexp, j + 3);
            float p4 = __shfl(pexp, j + 4), p5 = __shfl(pexp, j + 5);
            float p6 = __shfl(pexp, j + 6), p7 = __shfl(pexp, j + 7);
            uint2 r0 = *(const uint2*)(hcol + (size_t)s0 * DIM);
            uint2 r1 = *(const uint2*)(hcol + (size_t)s1 * DIM);
            uint2 r2 = *(const uint2*)(hcol + (size_t)s2 * DIM);
            uint2 r3 = *(const uint2*)(hcol + (size_t)s3 * DIM);
            uint2 r4 = *(const uint2*)(hcol + (size_t)s4 * DIM);
            uint2 r5 = *(const uint2*)(hcol + (size_t)s5 * DIM);
            uint2 r6 = *(const uint2*)(hcol + (size_t)s6 * DIM);
            uint2 r7 = *(const uint2*)(hcol + (size_t)s7 * DIM);
            acc0 = fmaf(p0, bflo(r0.x), acc0); acc1 = fmaf(p0, bfhi(r0.x), acc1);
            acc2 = fmaf(p0, bflo(r0.y), acc2); acc3 = fmaf(p0, bfhi(r0.y), acc3);
            acc0 = fmaf(p1, bflo(r1.x), acc0); acc1 = fmaf(p1, bfhi(r1.x), acc1);
            acc2 = fmaf(p1, bflo(r1.y), acc2); acc3 = fmaf(p1, bfhi(r1.y), acc3);
            acc0 = fmaf(p2, bflo(r2.x), acc0); acc1 = fmaf(p2, bfhi(r2.x), acc1);
            acc2 = fmaf(p2, bflo(r2.y), acc2); acc3 = fmaf(p2, bfhi(r2.y), acc3);
            acc0 = fmaf(p3, bflo(r3.x), acc0); acc1 = fmaf(p3, bfhi(r3.x), acc1);
            acc2 = fmaf(p3, bflo(r3.y), acc2); acc3 = fmaf(p3, bfhi(r3.y), acc3);
            acc0 = fmaf(p4, bflo(r4.x), acc0); acc1 = fmaf(p4, bfhi(r4.x), acc1);
            acc2 = fmaf(p4, bflo(r4.y), acc2); acc3 = fmaf(p4, bfhi(r4.y), acc3);
            acc0 = fmaf(p5, bflo(r5.x), acc0); acc1 = fmaf(p5, bfhi(r5.x), acc1);
            acc2 = fmaf(p5, bflo(r5.y), acc2); acc3 = fmaf(p5, bfhi(r5.y), acc3);
            acc0 = fmaf(p6, bflo(r6.x), acc0); acc1 = fmaf(p6, bfhi(r6.x), acc1);
            acc2 = fmaf(p6, bflo(r6.y), acc2); acc3 = fmaf(p6, bfhi(r6.y), acc3);
            acc0 = fmaf(p7, bflo(r7.x), acc0); acc1 = fmaf(p7, bfhi(r7.x), acc1);
            acc2 = fmaf(p7, bflo(r7.y), acc2); acc3 = fmaf(p7, bfhi(r7.y), acc3);
        }
        for (; j + 4 <= cn; j += 4) {
            int   s0 = __shfl(s, j),     s1 = __shfl(s, j + 1);
            int   s2 = __shfl(s, j + 2), s3 = __shfl(s, j + 3);
            float p0 = __shfl(pexp, j),     p1 = __shfl(pexp, j + 1);
            float p2 = __shfl(pexp, j + 2), p3 = __shfl(pexp, j + 3);
            uint2 r0 = *(const uint2*)(hcol + (size_t)s0 * DIM);
            uint2 r1 = *(const uint2*)(hcol + (size_t)s1 * DIM);
            uint2 r2 = *(const uint2*)(hcol + (size_t)s2 * DIM);
            uint2 r3 = *(const uint2*)(hcol + (size_t)s3 * DIM);
            acc0 = fmaf(p0, bflo(r0.x), acc0); acc1 = fmaf(p0, bfhi(r0.x), acc1);
            acc2 = fmaf(p0, bflo(r0.y), acc2); acc3 = fmaf(p0, bfhi(r0.y), acc3);
            acc0 = fmaf(p1, bflo(r1.x), acc0); acc1 = fmaf(p1, bfhi(r1.x), acc1);
            acc2 = fmaf(p1, bflo(r1.y), acc2); acc3 = fmaf(p1, bfhi(r1.y), acc3);
            acc0 = fmaf(p2, bflo(r2.x), acc0); acc1 = fmaf(p2, bfhi(r2.x), acc1);
            acc2 = fmaf(p2, bflo(r2.y), acc2); acc3 = fmaf(p2, bfhi(r2.y), acc3);
            acc0 = fmaf(p3, bflo(r3.x), acc0); acc1 = fmaf(p3, bfhi(r3.x), acc1);
            acc2 = fmaf(p3, bflo(r3.y), acc2); acc3 = fmaf(p3, bfhi(r3.y), acc3);
        }
        for (; j < cn; ++j) {
            int   sj = __shfl(s, j);
            float pj = __shfl(pexp, j);
            uint2 rv = *(const uint2*)(hcol + (size_t)sj * DIM);
            acc0 = fmaf(pj, bflo(rv.x), acc0); acc1 = fmaf(pj, bfhi(rv.x), acc1);
            acc2 = fmaf(pj, bflo(rv.y), acc2); acc3 = fmaf(pj, bfhi(rv.y), acc3);
        }
    }
    float z = zl;
#pragma unroll
    for (int o = 32; o; o >>= 1) z += __shfl_xor(z, o);
    const float inv = (end > beg) ? 1.f / (z + 1e-16f) : 0.f;
    float4 bb = *(const float4*)(bias + l * 4);
    float o0 = acc0 * inv + bb.x;
    float o1 = acc1 * inv + bb.y;
    float o2 = acc2 * inv + bb.z;
    float o3 = acc3 * inv + bb.w;
    if (do_silu) {
        o0 = o0 / (1.f + __expf(-o0));
        o1 = o1 / (1.f + __expf(-o1));
        o2 = o2 / (1.f + __expf(-o2));
        o3 = o3 / (1.f + __expf(-o3));
    }
    if (out_bf) {
        ushort us[4] = {f2bf(o0), f2bf(o1), f2bf(o2), f2bf(o3)};
        *(uint2*)(out_bf + (size_t)d * DIM + l * 4) = *(uint2*)us;
    } else {
        *(float4*)(out_f32 + (size_t)d * DIM + l * 4) = make_float4(o0, o1, o2, o3);
    }
}

// ----------- conflict detection (flags pre-zeroed by the fused memset).
__global__ __launch_bounds__(256)
void conflict_kernel(const int* __restrict__ head, const int* __restrict__ rel,
                     const int* __restrict__ g2l, const int* __restrict__ nbs,
                     int* __restrict__ flags) {
    int b = blockIdx.x;
    int rb = rel[b];
    if (rb < 4 || rb > 6) return;
    __shared__ int rd[KNB + 1];
    int t = threadIdx.x;
    if (t == 0) rd[KNB] = head[b];
    if (t < KNB) rd[t] = nbs[(size_t)g2l[head[b]] * KNB + t];
    __syncthreads();
    int rt = rel[t];
    int w = (t != b && rt >= 4 && rt <= 6) ? head[t] : -1;
    if (w >= 0) {
        bool hit = false;
#pragma unroll
        for (int k = 0; k <= KNB; ++k) hit |= (rd[k] == w);
        if (hit) { flags[b] = 1; flags[t] = 1; }
    }
}

// ----------- fused apply: blocks 0..255 = independent steps (rows untouched
// by any other step); block 256 = flagged steps in program order (each thread
// owns one column -> no barriers in the walk). Par/seq rows disjoint.
__global__ __launch_bounds__(256)
void apply_kernel(float* __restrict__ emb, const int* __restrict__ head,
                  const int* __restrict__ rel, const int* __restrict__ g2l,
                  const int* __restrict__ nbs, const float* __restrict__ wts,
                  const int* __restrict__ rhist, const int* __restrict__ flags) {
    const int t = threadIdx.x;
    if (blockIdx.x < BSZ) {
        int b = blockIdx.x;
        int r = rel[b];
        if (r < 4 || r > 6) return;
        if (flags[b]) return;
        int hi = head[b];
        int local = g2l[hi];
        int dg = rhist[(r - 4) * ND_ + local];
        float c = LAM * __expf(-LAM * (float)dg) + 0.2f;
        const int* __restrict__ nb = nbs + (size_t)local * KNB;
        const float* __restrict__ w = wts + (size_t)local * KNB;
        float v0 = 0.f, v1 = 0.f;
#pragma unroll
        for (int k = 0; k < KNB; k += 2) {
            v0 = fmaf(w[k],     emb[(size_t)nb[k] * DIM + t],     v0);
            v1 = fmaf(w[k + 1], emb[(size_t)nb[k + 1] * DIM + t], v1);
        }
        size_t idx = (size_t)hi * DIM + t;
        emb[idx] = c * (v0 + v1) + (1.f - c) * emb[idx];
        return;
    }
    // ---- sequential block ----
    __shared__ int   snb[BSZ][KNB];
    __shared__ float sw[BSZ][KNB];
    __shared__ int   sh[BSZ];
    __shared__ float sc[BSZ];
    __shared__ int   sf[BSZ];
    int r = rel[t];
    int dis = (r >= 4 && r <= 6);
    int hi = head[t];
    sh[t] = hi;
    sf[t] = dis ? flags[t] : 0;
    if (dis) {
        int local = g2l[hi];
        int dg = rhist[(r - 4) * ND_ + local];
        sc[t] = LAM * __expf(-LAM * (float)dg) + 0.2f;
#pragma unroll
        for (int k = 0; k < KNB; ++k) {
            snb[t][k] = nbs[(size_t)local * KNB + k];
            sw[t][k]  = wts[(size_t)local * KNB + k];
        }
    }
    __syncthreads();
    for (int b = 0; b < BSZ; ++b) {
        if (sf[b]) {
            int hh = sh[b];
            float c = sc[b];
            float v0 = 0.f, v1 = 0.f;
#pragma unroll
            for (int k = 0; k < KNB; k += 2) {
                v0 = fmaf(sw[b][k],     emb[(size_t)snb[b][k] * DIM + t],     v0);
                v1 = fmaf(sw[b][k + 1], emb[(size_t)snb[b][k + 1] * DIM + t], v1);
            }
            size_t idx = (size_t)hh * DIM + t;
            emb[idx] = c * (v0 + v1) + (1.f - c) * emb[idx];
        }
    }
}

// ------------------------------------------------------------------ decode
__global__ __launch_bounds__(256)
void decode_kernel(const float* __restrict__ emb, const int* __restrict__ head,
                   const int* __restrict__ rel, const int* __restrict__ tail,
                   const float* __restrict__ rel_emb, float* __restrict__ out) {
    int b = blockIdx.x, t = threadIdx.x;
    float v = emb[(size_t)head[b] * DIM + t] *
              rel_emb[(size_t)rel[b] * DIM + t] *
              emb[(size_t)tail[b] * DIM + t];
    __shared__ float red[4];
#pragma unroll
    for (int off = 32; off; off >>= 1) v += __shfl_down(v, off);
    int lane = t & 63, w = t >> 6;
    if (lane == 0) red[w] = v;
    __syncthreads();
    if (t == 0) {
        float s = red[0] + red[1] + red[2] + red[3];
        out[b] = 1.f / (1.f + expf(-s));
    }
}

// ------------------------------------------------------------------ launch
extern "C" void kernel_launch(void* const* d_in, const int* in_sizes, int n_in,
                              void* d_out, int out_size, void* d_ws, size_t ws_size,
                              hipStream_t stream) {
    const float* x        = (const float*)d_in[0];
    const int*   ei       = (const int*)d_in[1];
    const int*   head     = (const int*)d_in[2];
    const int*   rel      = (const int*)d_in[3];
    const int*   tail     = (const int*)d_in[4];
    const int*   g2l      = (const int*)d_in[5];
    const int*   res      = (const int*)d_in[6];
    const int*   nbs      = (const int*)d_in[7];
    const float* wts      = (const float*)d_in[8];
    const float* W1       = (const float*)d_in[9];
    const float* a1s      = (const float*)d_in[10];
    const float* a1d      = (const float*)d_in[11];
    const float* b1       = (const float*)d_in[12];
    const float* W2       = (const float*)d_in[13];
    const float* a2s      = (const float*)d_in[14];
    const float* a2d      = (const float*)d_in[15];
    const float* b2       = (const float*)d_in[16];
    const float* rel_emb  = (const float*)d_in[17];
    float* out = (float*)d_out;

    char* ws = (char*)d_ws;
    size_t off_b = 0;
    auto alloc = [&](size_t bytes) {
        void* pp = ws + off_b;
        off_b += (bytes + 255) & ~(size_t)255;
        return pp;
    };
    float*  bufB    = (float*)alloc((size_t)N_NODES * DIM * 4);  // layer-2 out (fp32)
    ushort* hb      = (ushort*)alloc((size_t)N_NODES * DIM * 2); // bf16 h rows (gemm out)
    ushort* h1b     = (ushort*)alloc((size_t)N_NODES * DIM * 2); // bf16 layer-1 out
    float*  hs      = (float*)alloc((size_t)N_NODES * 4);
    float*  hd      = (float*)alloc((size_t)N_NODES * 4);
    // ---- zeroed region (one fused memset) ----
    size_t z0 = off_b;
    int*    deg     = (int*)alloc((size_t)N_NODES * 4);
    int*    cnt     = (int*)alloc((size_t)N_NODES * 4);
    int*    rhist   = (int*)alloc((size_t)3 * ND_ * 4);
    int*    flags   = (int*)alloc((size_t)BSZ * 4);
    size_t z1 = off_b;
    // ------------------------------------------
    int*    offs    = (int*)alloc((size_t)(N_NODES + 1) * 4);
    int*    csr_src = (int*)alloc((size_t)N_EDGES * 4);
    int*    bsum    = (int*)alloc((size_t)NB_SCAN * 4);
    int*    bpre    = (int*)alloc((size_t)(NB_SCAN + 1) * 4);
    ushort* wpack1  = (ushort*)alloc((size_t)256 * 256 * 2);
    ushort* wpack2  = (ushort*)alloc((size_t)256 * 256 * 2);

    const int nodeBlocks4 = (N_NODES + 3) / 4;
    const int prepBlocks  = 32 + RH_BLKS + HIST_BLKS;

    // ---------------- prep: memset + {packW1|packW2|rel_hist|hist} ----------
    hipMemsetAsync(ws + z0, 0, z1 - z0, stream);   // deg + cnt + rhist + flags
    prep_kernel<<<prepBlocks, 256, 0, stream>>>(W1, W2, wpack1, wpack2,
                                                res, rhist, ei, deg);
    blockscan_kernel<<<NB_SCAN, 256, 0, stream>>>(deg, offs, bsum);
    scan_bsum_kernel<<<1, 256, 0, stream>>>(bsum, bpre);
    add_offsets_kernel<<<NB_SCAN, 256, 0, stream>>>(offs, bpre);
    scatter_kernel<<<HIST_BLKS, 256, 0, stream>>>(ei, offs, cnt, csr_src);

    // ---------------- layer 1 (A = x, fp32, staged in LDS) ----------------
    gemm_fused_kernel<1><<<GEMM_BLKS, 256, 0, stream>>>(x, nullptr, wpack1, hb,
                                                        a1s, a1d, hs, hd, N_NODES);
    gat_aggr_kernel<<<nodeBlocks4, 256, 0, stream>>>(offs, csr_src, hs, hd, hb, b1,
                                                     nullptr, h1b, 1);

    // ---------------- layer 2 (A = h1b, bf16, staged in LDS) ----------------
    gemm_fused_kernel<0><<<GEMM_BLKS, 256, 0, stream>>>(nullptr, h1b, wpack2, hb,
                                                        a2s, a2d, hs, hd, N_NODES);
    gat_aggr_kernel<<<nodeBlocks4, 256, 0, stream>>>(offs, csr_src, hs, hd, hb, b2,
                                                     bufB, nullptr, 0);

    // ---------------- scan (conflict -> fused apply) + decode ----------------
    conflict_kernel<<<BSZ, 256, 0, stream>>>(head, rel, g2l, nbs, flags);
    apply_kernel<<<BSZ + 1, 256, 0, stream>>>(bufB, head, rel, g2l, nbs, wts,
                                              rhist, flags);
    decode_kernel<<<BSZ, 256, 0, stream>>>(bufB, head, rel, tail, rel_emb, out);
}

// Round 15
// 383.384 us; speedup vs baseline: 1.1466x; 1.0049x over previous
//
#include <hip/hip_runtime.h>
#include <cstdint>

#define N_NODES 50000
#define N_EDGES 800000
#define DIM     256
#define BSZ     256
#define ND_     5000
#define KNB     16
#define ER_     20000
#define LAM     0.7f

typedef unsigned int uint;
typedef unsigned short ushort;
typedef __attribute__((ext_vector_type(8))) short bf16x8;
typedef __attribute__((ext_vector_type(4))) float f32x4;
typedef __attribute__((ext_vector_type(4))) float fvec4;   // nt-load compatible
typedef __attribute__((ext_vector_type(4))) uint  uvec4;   // nt-load compatible

#define NB_SCAN    ((N_NODES + 255) / 256)      // 196
#define GROWS      32                           // gemm tile rows
#define GEMM_BLKS  ((N_NODES + GROWS - 1) / GROWS)   // 1563
#define RH_BLKS    ((3 * ER_ + 255) / 256)      // 235
#define HIST_BLKS  ((N_EDGES + 255) / 256)      // 3125

__device__ __forceinline__ ushort f2bf(float f) {
    uint u = __float_as_uint(f);
    uint r = u + 0x7FFFu + ((u >> 16) & 1u);   // round-to-nearest-even
    return (ushort)(r >> 16);
}
__device__ __forceinline__ float bflo(uint u) { return __uint_as_float(u << 16); }
__device__ __forceinline__ float bfhi(uint u) { return __uint_as_float(u & 0xffff0000u); }

// fragment k-map: elem j, lane-group lg -> kk=(j&3)+lg*4+(j>>2)*16, same
// bijection for A and B fragments (permutation cancels inside the MFMA dot).

// ---------------- pack W [K=256,N=256] f32 -> frag order (device body) ----
__device__ __forceinline__ void pack_b_body(const float* __restrict__ W,
                                            ushort* __restrict__ out, int nt, int t) {
    const int l  = t & 63;
    const int kt0 = (t >> 6) * 2;
    const int n  = nt * 16 + (l & 15);
    const int lg = l >> 4;
#pragma unroll
    for (int p = 0; p < 2; ++p) {
        int kt = kt0 + p;
        ushort us[8];
#pragma unroll
        for (int j = 0; j < 8; ++j) {
            int kk = (j & 3) + lg * 4 + (j >> 2) * 16;
            us[j] = f2bf(W[(size_t)(kt * 32 + kk) * 256 + n]);
        }
        *(uint4*)(out + ((size_t)(nt * 8 + kt) * 64 + l) * 8) = *(uint4*)us;
    }
}

// -------- merged prep: pack W1 | pack W2 | rel-hist | dst-degree hist -----
__global__ __launch_bounds__(256)
void prep_kernel(const float* __restrict__ W1, const float* __restrict__ W2,
                 ushort* __restrict__ wp1, ushort* __restrict__ wp2,
                 const int* __restrict__ res, int* __restrict__ rhist,
                 const int* __restrict__ ei, int* __restrict__ deg) {
    const int b = blockIdx.x, t = threadIdx.x;
    if (b < 16)       { pack_b_body(W1, wp1, b, t);      return; }
    if (b < 32)       { pack_b_body(W2, wp2, b - 16, t); return; }
    if (b < 32 + RH_BLKS) {
        int i = (b - 32) * 256 + t;
        if (i < 3 * ER_) atomicAdd(&rhist[(i / ER_) * ND_ + __builtin_nontemporal_load(&res[i])], 1);
        return;
    }
    int e = (b - 32 - RH_BLKS) * 256 + t;
    if (e < N_EDGES) atomicAdd(&deg[__builtin_nontemporal_load(&ei[N_EDGES + e])], 1);
}

// -------- LDS-staged bf16 MFMA GEMM + LDS-transpose epilogue --------------
// H[M,256] (bf16 row-major) = A @ B ; hs/hd = H @ a_src / H @ a_dst.
// A staged 32x256 per block (XOR-swizzled chunks, conflict-free both ways).
// A-stage loads are NON-TEMPORAL: A is stream-once data; keeping it out of
// L2 preserves the 128 KB wpack working set across blocks (R14 main bet).
template<int SRCF32>
__global__ __launch_bounds__(256)
void gemm_fused_kernel(const float* __restrict__ Af, const ushort* __restrict__ Ab,
                       const ushort* __restrict__ Bp, ushort* __restrict__ H,
                       const float* __restrict__ a_src, const float* __restrict__ a_dst,
                       float* __restrict__ hs, float* __restrict__ hd, int M) {
    __shared__ uint2 lda[GROWS * 64];        // 16 KiB; reused as H-tile in epilogue
    const int t = threadIdx.x;
    const int w = t >> 6;
    const int l = t & 63;
    const int rb = blockIdx.x * GROWS;

    // ---- stage A (coalesced, non-temporal) ----
    if (SRCF32) {
#pragma unroll
        for (int u = 0; u < 8; ++u) {
            int f = t + u * 256;              // float4 index; 64 per row
            int r = f >> 6;
            int cq = f & 63;                  // chunk (4 cols)
            int grow = rb + r;
            fvec4 v = (fvec4){0.f, 0.f, 0.f, 0.f};
            if (grow < M)
                v = __builtin_nontemporal_load((const fvec4*)(Af + (size_t)grow * 256 + cq * 4));
            uint2 o;
            o.x = (uint)f2bf(v.x) | ((uint)f2bf(v.y) << 16);
            o.y = (uint)f2bf(v.z) | ((uint)f2bf(v.w) << 16);
            lda[r * 64 + (cq ^ (r & 15))] = o;
        }
    } else {
#pragma unroll
        for (int u = 0; u < 4; ++u) {
            int f = t + u * 256;              // uint4 index; 32 per row
            int r = f >> 5;
            int p = f & 31;
            int grow = rb + r;
            uvec4 v = (uvec4){0u, 0u, 0u, 0u};
            if (grow < M)
                v = __builtin_nontemporal_load((const uvec4*)(Ab + (size_t)grow * 256 + p * 8));
            int c = p * 2;
            lda[r * 64 + ( c      ^ (r & 15))] = make_uint2(v.x, v.y);
            lda[r * 64 + ((c + 1) ^ (r & 15))] = make_uint2(v.z, v.w);
        }
    }
    __syncthreads();

    // ---- MFMA ----
    const int cb = l & 15;
    const int lg = l >> 4;
    f32x4 acc[2][4];
#pragma unroll
    for (int i = 0; i < 2; ++i)
#pragma unroll
        for (int j = 0; j < 4; ++j) acc[i][j] = (f32x4){0.f, 0.f, 0.f, 0.f};

    for (int kt = 0; kt < 8; ++kt) {
        bf16x8 af[2], bfr[4];
#pragma unroll
        for (int mi = 0; mi < 2; ++mi) {
            int row = mi * 16 + cb;
            uint2 lo = lda[row * 64 + ((kt * 8 + lg)     ^ cb)];
            uint2 hi = lda[row * 64 + ((kt * 8 + lg + 4) ^ cb)];
            uint4 cmb; cmb.x = lo.x; cmb.y = lo.y; cmb.z = hi.x; cmb.w = hi.y;
            af[mi] = *(bf16x8*)&cmb;
        }
#pragma unroll
        for (int ni = 0; ni < 4; ++ni)
            bfr[ni] = *(const bf16x8*)(Bp + ((size_t)((w * 4 + ni) * 8 + kt) * 64 + l) * 8);
#pragma unroll
        for (int mi = 0; mi < 2; ++mi)
#pragma unroll
            for (int ni = 0; ni < 4; ++ni)
                acc[mi][ni] = __builtin_amdgcn_mfma_f32_16x16x32_bf16(
                    af[mi], bfr[ni], acc[mi][ni], 0, 0, 0);
    }

    // ---- epilogue: acc -> LDS bf16 tile (chunk-swizzled), then coalesced out
    __syncthreads();                          // all lda reads done; reuse buffer
    ushort* h_lds = (ushort*)lda;             // [32][256] bf16 = 16 KiB
    const int rbase = (l >> 4) * 4;           // C/D: col=lane&15, row=(lane>>4)*4+reg
#pragma unroll
    for (int mi = 0; mi < 2; ++mi) {
#pragma unroll
        for (int r = 0; r < 4; ++r) {
            int row = mi * 16 + rbase + r;
            int sw  = ((row >> 2) & 3) << 1;  // chunk XOR: spreads 4 row-groups
#pragma unroll
            for (int ni = 0; ni < 4; ++ni) {
                int col = (w * 4 + ni) * 16 + cb;
                int ch  = (col >> 3) ^ sw;
                h_lds[row * 256 + ch * 8 + (col & 7)] = f2bf(acc[mi][ni][r]);
            }
        }
    }
    __syncthreads();
    // write-out + fused dots: per iter, 32 consecutive half-wave lanes own one row
#pragma unroll
    for (int it = 0; it < 4; ++it) {
        int row = it * 8 + (t >> 5);          // 0..31
        int chl = t & 31;                     // logical chunk (8 elems)
        int sw  = ((row >> 2) & 3) << 1;
        uint4 v = *(const uint4*)(h_lds + row * 256 + (chl ^ sw) * 8);
        int c0  = chl * 8;
        float4 as0 = *(const float4*)(a_src + c0);
        float4 as1 = *(const float4*)(a_src + c0 + 4);
        float4 ad0 = *(const float4*)(a_dst + c0);
        float4 ad1 = *(const float4*)(a_dst + c0 + 4);
        float e0 = bflo(v.x), e1 = bfhi(v.x), e2 = bflo(v.y), e3 = bfhi(v.y);
        float e4 = bflo(v.z), e5 = bfhi(v.z), e6 = bflo(v.w), e7 = bfhi(v.w);
        float ps = e0 * as0.x + e1 * as0.y + e2 * as0.z + e3 * as0.w
                 + e4 * as1.x + e5 * as1.y + e6 * as1.z + e7 * as1.w;
        float pd = e0 * ad0.x + e1 * ad0.y + e2 * ad0.z + e3 * ad0.w
                 + e4 * ad1.x + e5 * ad1.y + e6 * ad1.z + e7 * ad1.w;
#pragma unroll
        for (int o = 16; o; o >>= 1) {
            ps += __shfl_down(ps, o, 32);
            pd += __shfl_down(pd, o, 32);
        }
        int grow = rb + row;
        if (grow < M) {
            *(uint4*)(H + (size_t)grow * 256 + c0) = v;
            if (chl == 0) { hs[grow] = ps; hd[grow] = pd; }
        }
    }
}

// -------- two-level parallel exclusive scan of deg -> offs --------
__global__ __launch_bounds__(256)
void blockscan_kernel(const int* __restrict__ deg, int* __restrict__ off,
                      int* __restrict__ bsum) {
    __shared__ int s[256];
    const int b = blockIdx.x, t = threadIdx.x;
    const int idx = b * 256 + t;
    int v = (idx < N_NODES) ? deg[idx] : 0;
    s[t] = v;
    __syncthreads();
    for (int o = 1; o < 256; o <<= 1) {
        int x = (t >= o) ? s[t - o] : 0;
        __syncthreads();
        s[t] += x;
        __syncthreads();
    }
    if (idx < N_NODES) off[idx] = s[t] - v;
    if (t == 255) bsum[b] = s[255];
}

__global__ __launch_bounds__(256)
void scan_bsum_kernel(const int* __restrict__ bsum, int* __restrict__ bpre) {
    __shared__ int s[256];
    const int t = threadIdx.x;
    int v = (t < NB_SCAN) ? bsum[t] : 0;
    s[t] = v;
    __syncthreads();
    for (int o = 1; o < 256; o <<= 1) {
        int x = (t >= o) ? s[t - o] : 0;
        __syncthreads();
        s[t] += x;
        __syncthreads();
    }
    if (t < NB_SCAN) bpre[t] = s[t] - v;
    if (t == 255) bpre[NB_SCAN] = s[255];
}

__global__ __launch_bounds__(256)
void add_offsets_kernel(int* __restrict__ off, const int* __restrict__ bpre) {
    const int b = blockIdx.x, t = threadIdx.x;
    const int idx = b * 256 + t;
    if (idx < N_NODES) off[idx] += bpre[b];
    if (b == NB_SCAN - 1 && t == 255) off[N_NODES] = bpre[NB_SCAN];
}

// cnt-based scatter (offs left intact -> rocprof replay-safe)
__global__ __launch_bounds__(256)
void scatter_kernel(const int* __restrict__ ei, const int* __restrict__ off,
                    int* __restrict__ cnt, int* __restrict__ csr_src) {
    int e = blockIdx.x * 256 + threadIdx.x;
    if (e >= N_EDGES) return;
    int d = __builtin_nontemporal_load(&ei[N_EDGES + e]);
    int srcv = __builtin_nontemporal_load(&ei[e]);
    int pos = atomicAdd(&cnt[d], 1);
    csr_src[off[d] + pos] = srcv;
}

// ----------------- fused GAT edge stage: wave-per-dst, no max, no barriers
// 8x-unrolled gather: 8 independent row loads in flight per latency wait.
// csr_src read non-temporally (stream-once) to keep hb rows hotter in L2.
__global__ __launch_bounds__(256)
void gat_aggr_kernel(const int* __restrict__ off, const int* __restrict__ csr_src,
                     const float* __restrict__ hs, const float* __restrict__ hd,
                     const ushort* __restrict__ hb, const float* __restrict__ bias,
                     float* __restrict__ out_f32, ushort* __restrict__ out_bf,
                     int do_silu) {
    const int d = blockIdx.x * 4 + (threadIdx.x >> 6);
    const int l = threadIdx.x & 63;
    if (d >= N_NODES) return;
    const int beg = off[d], end = off[d + 1];
    const float hdd = hd[d];

    float acc0 = 0.f, acc1 = 0.f, acc2 = 0.f, acc3 = 0.f;
    float zl = 0.f;
    const ushort* __restrict__ hcol = hb + l * 4;

    for (int c0 = beg; c0 < end; c0 += 64) {
        const int cn = min(end - c0, 64);
        int s = 0; float pexp = 0.f;
        if (l < cn) {
            s = __builtin_nontemporal_load(&csr_src[c0 + l]);
            float v = hs[s] + hdd;
            v = (v >= 0.f) ? v : 0.2f * v;
            pexp = __expf(v);
        }
        zl += pexp;
        int j = 0;
        for (; j + 8 <= cn; j += 8) {
            int   s0 = __shfl(s, j),     s1 = __shfl(s, j + 1);
            int   s2 = __shfl(s, j + 2), s3 = __shfl(s, j + 3);
            int   s4 = __shfl(s, j + 4), s5 = __shfl(s, j + 5);
            int   s6 = __shfl(s, j + 6), s7 = __shfl(s, j + 7);
            float p0 = __shfl(pexp, j),     p1 = __shfl(pexp, j + 1);
            float p2 = __shfl(pexp, j + 2), p3 = __shfl(pexp, j + 3);
            float p4 = __shfl(pexp, j + 4), p5 = __shfl(pexp, j + 5);
            float p6 = __shfl(pexp, j + 6), p7 = __shfl(pexp, j + 7);
            uint2 r0 = *(const uint2*)(hcol + (size_t)s0 * DIM);
            uint2 r1 = *(const uint2*)(hcol + (size_t)s1 * DIM);
            uint2 r2 = *(const uint2*)(hcol + (size_t)s2 * DIM);
            uint2 r3 = *(const uint2*)(hcol + (size_t)s3 * DIM);
            uint2 r4 = *(const uint2*)(hcol + (size_t)s4 * DIM);
            uint2 r5 = *(const uint2*)(hcol + (size_t)s5 * DIM);
            uint2 r6 = *(const uint2*)(hcol + (size_t)s6 * DIM);
            uint2 r7 = *(const uint2*)(hcol + (size_t)s7 * DIM);
            acc0 = fmaf(p0, bflo(r0.x), acc0); acc1 = fmaf(p0, bfhi(r0.x), acc1);
            acc2 = fmaf(p0, bflo(r0.y), acc2); acc3 = fmaf(p0, bfhi(r0.y), acc3);
            acc0 = fmaf(p1, bflo(r1.x), acc0); acc1 = fmaf(p1, bfhi(r1.x), acc1);
            acc2 = fmaf(p1, bflo(r1.y), acc2); acc3 = fmaf(p1, bfhi(r1.y), acc3);
            acc0 = fmaf(p2, bflo(r2.x), acc0); acc1 = fmaf(p2, bfhi(r2.x), acc1);
            acc2 = fmaf(p2, bflo(r2.y), acc2); acc3 = fmaf(p2, bfhi(r2.y), acc3);
            acc0 = fmaf(p3, bflo(r3.x), acc0); acc1 = fmaf(p3, bfhi(r3.x), acc1);
            acc2 = fmaf(p3, bflo(r3.y), acc2); acc3 = fmaf(p3, bfhi(r3.y), acc3);
            acc0 = fmaf(p4, bflo(r4.x), acc0); acc1 = fmaf(p4, bfhi(r4.x), acc1);
            acc2 = fmaf(p4, bflo(r4.y), acc2); acc3 = fmaf(p4, bfhi(r4.y), acc3);
            acc0 = fmaf(p5, bflo(r5.x), acc0); acc1 = fmaf(p5, bfhi(r5.x), acc1);
            acc2 = fmaf(p5, bflo(r5.y), acc2); acc3 = fmaf(p5, bfhi(r5.y), acc3);
            acc0 = fmaf(p6, bflo(r6.x), acc0); acc1 = fmaf(p6, bfhi(r6.x), acc1);
            acc2 = fmaf(p6, bflo(r6.y), acc2); acc3 = fmaf(p6, bfhi(r6.y), acc3);
            acc0 = fmaf(p7, bflo(r7.x), acc0); acc1 = fmaf(p7, bfhi(r7.x), acc1);
            acc2 = fmaf(p7, bflo(r7.y), acc2); acc3 = fmaf(p7, bfhi(r7.y), acc3);
        }
        for (; j + 4 <= cn; j += 4) {
            int   s0 = __shfl(s, j),     s1 = __shfl(s, j + 1);
            int   s2 = __shfl(s, j + 2), s3 = __shfl(s, j + 3);
            float p0 = __shfl(pexp, j),     p1 = __shfl(pexp, j + 1);
            float p2 = __shfl(pexp, j + 2), p3 = __shfl(pexp, j + 3);
            uint2 r0 = *(const uint2*)(hcol + (size_t)s0 * DIM);
            uint2 r1 = *(const uint2*)(hcol + (size_t)s1 * DIM);
            uint2 r2 = *(const uint2*)(hcol + (size_t)s2 * DIM);
            uint2 r3 = *(const uint2*)(hcol + (size_t)s3 * DIM);
            acc0 = fmaf(p0, bflo(r0.x), acc0); acc1 = fmaf(p0, bfhi(r0.x), acc1);
            acc2 = fmaf(p0, bflo(r0.y), acc2); acc3 = fmaf(p0, bfhi(r0.y), acc3);
            acc0 = fmaf(p1, bflo(r1.x), acc0); acc1 = fmaf(p1, bfhi(r1.x), acc1);
            acc2 = fmaf(p1, bflo(r1.y), acc2); acc3 = fmaf(p1, bfhi(r1.y), acc3);
            acc0 = fmaf(p2, bflo(r2.x), acc0); acc1 = fmaf(p2, bfhi(r2.x), acc1);
            acc2 = fmaf(p2, bflo(r2.y), acc2); acc3 = fmaf(p2, bfhi(r2.y), acc3);
            acc0 = fmaf(p3, bflo(r3.x), acc0); acc1 = fmaf(p3, bfhi(r3.x), acc1);
            acc2 = fmaf(p3, bflo(r3.y), acc2); acc3 = fmaf(p3, bfhi(r3.y), acc3);
        }
        for (; j < cn; ++j) {
            int   sj = __shfl(s, j);
            float pj = __shfl(pexp, j);
            uint2 rv = *(const uint2*)(hcol + (size_t)sj * DIM);
            acc0 = fmaf(pj, bflo(rv.x), acc0); acc1 = fmaf(pj, bfhi(rv.x), acc1);
            acc2 = fmaf(pj, bflo(rv.y), acc2); acc3 = fmaf(pj, bfhi(rv.y), acc3);
        }
    }
    float z = zl;
#pragma unroll
    for (int o = 32; o; o >>= 1) z += __shfl_xor(z, o);
    const float inv = (end > beg) ? 1.f / (z + 1e-16f) : 0.f;
    float4 bb = *(const float4*)(bias + l * 4);
    float o0 = acc0 * inv + bb.x;
    float o1 = acc1 * inv + bb.y;
    float o2 = acc2 * inv + bb.z;
    float o3 = acc3 * inv + bb.w;
    if (do_silu) {
        o0 = o0 / (1.f + __expf(-o0));
        o1 = o1 / (1.f + __expf(-o1));
        o2 = o2 / (1.f + __expf(-o2));
        o3 = o3 / (1.f + __expf(-o3));
    }
    if (out_bf) {
        ushort us[4] = {f2bf(o0), f2bf(o1), f2bf(o2), f2bf(o3)};
        *(uint2*)(out_bf + (size_t)d * DIM + l * 4) = *(uint2*)us;
    } else {
        *(float4*)(out_f32 + (size_t)d * DIM + l * 4) = make_float4(o0, o1, o2, o3);
    }
}

// ----------- conflict detection (flags pre-zeroed by the fused memset).
__global__ __launch_bounds__(256)
void conflict_kernel(const int* __restrict__ head, const int* __restrict__ rel,
                     const int* __restrict__ g2l, const int* __restrict__ nbs,
                     int* __restrict__ flags) {
    int b = blockIdx.x;
    int rb = rel[b];
    if (rb < 4 || rb > 6) return;
    __shared__ int rd[KNB + 1];
    int t = threadIdx.x;
    if (t == 0) rd[KNB] = head[b];
    if (t < KNB) rd[t] = nbs[(size_t)g2l[head[b]] * KNB + t];
    __syncthreads();
    int rt = rel[t];
    int w = (t != b && rt >= 4 && rt <= 6) ? head[t] : -1;
    if (w >= 0) {
        bool hit = false;
#pragma unroll
        for (int k = 0; k <= KNB; ++k) hit |= (rd[k] == w);
        if (hit) { flags[b] = 1; flags[t] = 1; }
    }
}

// ----------- fused apply: blocks 0..255 = independent steps (rows untouched
// by any other step); block 256 = flagged steps in program order (each thread
// owns one column -> no barriers in the walk). Par/seq rows disjoint.
__global__ __launch_bounds__(256)
void apply_kernel(float* __restrict__ emb, const int* __restrict__ head,
                  const int* __restrict__ rel, const int* __restrict__ g2l,
                  const int* __restrict__ nbs, const float* __restrict__ wts,
                  const int* __restrict__ rhist, const int* __restrict__ flags) {
    const int t = threadIdx.x;
    if (blockIdx.x < BSZ) {
        int b = blockIdx.x;
        int r = rel[b];
        if (r < 4 || r > 6) return;
        if (flags[b]) return;
        int hi = head[b];
        int local = g2l[hi];
        int dg = rhist[(r - 4) * ND_ + local];
        float c = LAM * __expf(-LAM * (float)dg) + 0.2f;
        const int* __restrict__ nb = nbs + (size_t)local * KNB;
        const float* __restrict__ w = wts + (size_t)local * KNB;
        float v0 = 0.f, v1 = 0.f;
#pragma unroll
        for (int k = 0; k < KNB; k += 2) {
            v0 = fmaf(w[k],     emb[(size_t)nb[k] * DIM + t],     v0);
            v1 = fmaf(w[k + 1], emb[(size_t)nb[k + 1] * DIM + t], v1);
        }
        size_t idx = (size_t)hi * DIM + t;
        emb[idx] = c * (v0 + v1) + (1.f - c) * emb[idx];
        return;
    }
    // ---- sequential block ----
    __shared__ int   snb[BSZ][KNB];
    __shared__ float sw[BSZ][KNB];
    __shared__ int   sh[BSZ];
    __shared__ float sc[BSZ];
    __shared__ int   sf[BSZ];
    int r = rel[t];
    int dis = (r >= 4 && r <= 6);
    int hi = head[t];
    sh[t] = hi;
    sf[t] = dis ? flags[t] : 0;
    if (dis) {
        int local = g2l[hi];
        int dg = rhist[(r - 4) * ND_ + local];
        sc[t] = LAM * __expf(-LAM * (float)dg) + 0.2f;
#pragma unroll
        for (int k = 0; k < KNB; ++k) {
            snb[t][k] = nbs[(size_t)local * KNB + k];
            sw[t][k]  = wts[(size_t)local * KNB + k];
        }
    }
    __syncthreads();
    for (int b = 0; b < BSZ; ++b) {
        if (sf[b]) {
            int hh = sh[b];
            float c = sc[b];
            float v0 = 0.f, v1 = 0.f;
#pragma unroll
            for (int k = 0; k < KNB; k += 2) {
                v0 = fmaf(sw[b][k],     emb[(size_t)snb[b][k] * DIM + t],     v0);
                v1 = fmaf(sw[b][k + 1], emb[(size_t)snb[b][k + 1] * DIM + t], v1);
            }
            size_t idx = (size_t)hh * DIM + t;
            emb[idx] = c * (v0 + v1) + (1.f - c) * emb[idx];
        }
    }
}

// ------------------------------------------------------------------ decode
__global__ __launch_bounds__(256)
void decode_kernel(const float* __restrict__ emb, const int* __restrict__ head,
                   const int* __restrict__ rel, const int* __restrict__ tail,
                   const float* __restrict__ rel_emb, float* __restrict__ out) {
    int b = blockIdx.x, t = threadIdx.x;
    float v = emb[(size_t)head[b] * DIM + t] *
              rel_emb[(size_t)rel[b] * DIM + t] *
              emb[(size_t)tail[b] * DIM + t];
    __shared__ float red[4];
#pragma unroll
    for (int off = 32; off; off >>= 1) v += __shfl_down(v, off);
    int lane = t & 63, w = t >> 6;
    if (lane == 0) red[w] = v;
    __syncthreads();
    if (t == 0) {
        float s = red[0] + red[1] + red[2] + red[3];
        out[b] = 1.f / (1.f + expf(-s));
    }
}

// ------------------------------------------------------------------ launch
extern "C" void kernel_launch(void* const* d_in, const int* in_sizes, int n_in,
                              void* d_out, int out_size, void* d_ws, size_t ws_size,
                              hipStream_t stream) {
    const float* x        = (const float*)d_in[0];
    const int*   ei       = (const int*)d_in[1];
    const int*   head     = (const int*)d_in[2];
    const int*   rel      = (const int*)d_in[3];
    const int*   tail     = (const int*)d_in[4];
    const int*   g2l      = (const int*)d_in[5];
    const int*   res      = (const int*)d_in[6];
    const int*   nbs      = (const int*)d_in[7];
    const float* wts      = (const float*)d_in[8];
    const float* W1       = (const float*)d_in[9];
    const float* a1s      = (const float*)d_in[10];
    const float* a1d      = (const float*)d_in[11];
    const float* b1       = (const float*)d_in[12];
    const float* W2       = (const float*)d_in[13];
    const float* a2s      = (const float*)d_in[14];
    const float* a2d      = (const float*)d_in[15];
    const float* b2       = (const float*)d_in[16];
    const float* rel_emb  = (const float*)d_in[17];
    float* out = (float*)d_out;

    char* ws = (char*)d_ws;
    size_t off_b = 0;
    auto alloc = [&](size_t bytes) {
        void* pp = ws + off_b;
        off_b += (bytes + 255) & ~(size_t)255;
        return pp;
    };
    float*  bufB    = (float*)alloc((size_t)N_NODES * DIM * 4);  // layer-2 out (fp32)
    ushort* hb      = (ushort*)alloc((size_t)N_NODES * DIM * 2); // bf16 h rows (gemm out)
    ushort* h1b     = (ushort*)alloc((size_t)N_NODES * DIM * 2); // bf16 layer-1 out
    float*  hs      = (float*)alloc((size_t)N_NODES * 4);
    float*  hd      = (float*)alloc((size_t)N_NODES * 4);
    // ---- zeroed region (one fused memset) ----
    size_t z0 = off_b;
    int*    deg     = (int*)alloc((size_t)N_NODES * 4);
    int*    cnt     = (int*)alloc((size_t)N_NODES * 4);
    int*    rhist   = (int*)alloc((size_t)3 * ND_ * 4);
    int*    flags   = (int*)alloc((size_t)BSZ * 4);
    size_t z1 = off_b;
    // ------------------------------------------
    int*    offs    = (int*)alloc((size_t)(N_NODES + 1) * 4);
    int*    csr_src = (int*)alloc((size_t)N_EDGES * 4);
    int*    bsum    = (int*)alloc((size_t)NB_SCAN * 4);
    int*    bpre    = (int*)alloc((size_t)(NB_SCAN + 1) * 4);
    ushort* wpack1  = (ushort*)alloc((size_t)256 * 256 * 2);
    ushort* wpack2  = (ushort*)alloc((size_t)256 * 256 * 2);

    const int nodeBlocks4 = (N_NODES + 3) / 4;
    const int prepBlocks  = 32 + RH_BLKS + HIST_BLKS;

    // ---------------- prep: memset + {packW1|packW2|rel_hist|hist} ----------
    hipMemsetAsync(ws + z0, 0, z1 - z0, stream);   // deg + cnt + rhist + flags
    prep_kernel<<<prepBlocks, 256, 0, stream>>>(W1, W2, wpack1, wpack2,
                                                res, rhist, ei, deg);
    blockscan_kernel<<<NB_SCAN, 256, 0, stream>>>(deg, offs, bsum);
    scan_bsum_kernel<<<1, 256, 0, stream>>>(bsum, bpre);
    add_offsets_kernel<<<NB_SCAN, 256, 0, stream>>>(offs, bpre);
    scatter_kernel<<<HIST_BLKS, 256, 0, stream>>>(ei, offs, cnt, csr_src);

    // ---------------- layer 1 (A = x, fp32, staged in LDS) ----------------
    gemm_fused_kernel<1><<<GEMM_BLKS, 256, 0, stream>>>(x, nullptr, wpack1, hb,
                                                        a1s, a1d, hs, hd, N_NODES);
    gat_aggr_kernel<<<nodeBlocks4, 256, 0, stream>>>(offs, csr_src, hs, hd, hb, b1,
                                                     nullptr, h1b, 1);

    // ---------------- layer 2 (A = h1b, bf16, staged in LDS) ----------------
    gemm_fused_kernel<0><<<GEMM_BLKS, 256, 0, stream>>>(nullptr, h1b, wpack2, hb,
                                                        a2s, a2d, hs, hd, N_NODES);
    gat_aggr_kernel<<<nodeBlocks4, 256, 0, stream>>>(offs, csr_src, hs, hd, hb, b2,
                                                     bufB, nullptr, 0);

    // ---------------- scan (conflict -> fused apply) + decode ----------------
    conflict_kernel<<<BSZ, 256, 0, stream>>>(head, rel, g2l, nbs, flags);
    apply_kernel<<<BSZ + 1, 256, 0, stream>>>(bufB, head, rel, g2l, nbs, wts,
                                              rhist, flags);
    decode_kernel<<<BSZ, 256, 0, stream>>>(bufB, head, rel, tail, rel_emb, out);
}